// Round 7
// baseline (984.358 us; speedup 1.0000x reference)
//
#include <hip/hip_runtime.h>
#include <stdint.h>

typedef unsigned short u16;
typedef unsigned int u32;
typedef __attribute__((ext_vector_type(8))) short s8v;   // 8 bf16 = 4 VGPR (MFMA A/B frag)
typedef __attribute__((ext_vector_type(4))) float f4v;   // MFMA C/D frag
typedef __attribute__((ext_vector_type(8))) u16 u16x8;

// ---------- bf16 helpers ----------
__device__ __forceinline__ float bf2f(u16 u){
  union { u32 i; float f; } v; v.i = ((u32)u) << 16; return v.f;
}
__device__ __forceinline__ u16 f2bf(float f){
  union { float f; u32 i; } v; v.f = f;
  u32 i = v.i;
  return (u16)((i + 0x7fffu + ((i >> 16) & 1u)) >> 16); // RNE
}
__device__ __forceinline__ float sgnf(float w){
  return (w > 0.f) ? 1.f : ((w < 0.f) ? -1.f : 0.f);
}
__device__ __forceinline__ u16 sgn_bf(float w){
  return (w > 0.f) ? (u16)0x3F80 : ((w < 0.f) ? (u16)0xBF80 : (u16)0);
}

// ---------- block reduction (256 threads = 4 waves) ----------
__device__ __forceinline__ void block_reduce2(float& a, float& b){
  #pragma unroll
  for (int off = 32; off > 0; off >>= 1){
    a += __shfl_down(a, off);
    b += __shfl_down(b, off);
  }
  __shared__ float ra[4], rb[4];
  int lane = threadIdx.x & 63, w = threadIdx.x >> 6;
  __syncthreads();
  if (lane == 0){ ra[w] = a; rb[w] = b; }
  __syncthreads();
  if (threadIdx.x == 0){
    a = ra[0] + ra[1] + ra[2] + ra[3];
    b = rb[0] + rb[1] + rb[2] + rb[3];
  }
}

__global__ void k_zero(float* __restrict__ p, int n){
  int i = blockIdx.x * blockDim.x + threadIdx.x;
  if (i < n) p[i] = 0.f;
}

// ---------- sum(|w|) for the 4 weight tensors ----------
__global__ __launch_bounds__(256) void k_absum(const float* __restrict__ w1, const float* __restrict__ w2,
                                               const float* __restrict__ wfc1, const float* __restrict__ wfc2,
                                               float* __restrict__ absum){
  int b = blockIdx.x, t = threadIdx.x;
  const float* src; int n0, cnt, slot;
  if (b < 64)      { src = wfc1; slot = 2; cnt = 2097152/64; n0 = b * cnt; }
  else if (b < 96) { src = w2;   slot = 1; cnt = 73728/32;   n0 = (b-64) * cnt; }
  else if (b == 96){ src = w1;   slot = 0; cnt = 1728;       n0 = 0; }
  else             { src = wfc2; slot = 3; cnt = 2560;       n0 = 0; }
  float s = 0.f, d = 0.f;
  for (int i = t; i < cnt; i += 256) s += fabsf(src[n0 + i]);
  block_reduce2(s, d);
  if (t == 0) atomicAdd(absum + slot, s);
}

// ---------- generate all quantized weight forms ----------
// qw1t: fp32 [27 k][64 co] for conv1 VALU
// qw2b: bf16 MFMA B-frags for conv2, frag fid=(s*2+ks)*8+nt, elem idx=fid*512+lane*8+j
//       co = (lane&15)*8 + nt   (co permutation -> coalesced channel-last stores)
//       c  = ks*32 + (lane>>4)*8 + j
// qfc1b: bf16 MFMA B-frags for fc1, frag = kstep*16+nt; k_phys = kstep*32+(lane>>4)*8+j
//       p2 is channel-last: k_phys = px*128+c  ->  logical k = c*64+px
// qwfc2: fp32 sign [10][256]
__global__ __launch_bounds__(256) void k_signgen(const float* __restrict__ w1, const float* __restrict__ w2,
                                                 const float* __restrict__ wfc1, const float* __restrict__ wfc2,
                                                 float* __restrict__ qw1t, u16* __restrict__ qw2b,
                                                 u16* __restrict__ qfc1b, float* __restrict__ qwfc2){
  int i = blockIdx.x * 256 + threadIdx.x;
  if (i < 2097152){
    int j = i & 7, lane = (i >> 3) & 63, fid = i >> 9;
    int kstep = fid >> 4, nt = fid & 15;
    int co = nt*16 + (lane & 15);
    int k_phys = kstep*32 + (lane >> 4)*8 + j;
    int px = k_phys >> 7, c = k_phys & 127;
    qfc1b[i] = sgn_bf(wfc1[(size_t)co*8192 + c*64 + px]);
  } else if (i < 2097152 + 73728){
    int i2 = i - 2097152;
    int j = i2 & 7, lane = (i2 >> 3) & 63, fid = i2 >> 9;  // 0..143
    int s = fid >> 4, ks = (fid >> 3) & 1, nt = fid & 7;
    int co = (lane & 15)*8 + nt;
    int c = ks*32 + (lane >> 4)*8 + j;
    qw2b[i2] = sgn_bf(w2[((size_t)co*64 + c)*9 + s]);
  } else if (i < 2097152 + 73728 + 1728){
    int i3 = i - (2097152 + 73728);
    int co = i3 / 27, k = i3 % 27;
    qw1t[k*64 + co] = sgnf(w1[i3]);
  } else if (i < 2097152 + 73728 + 1728 + 2560){
    int i4 = i - (2097152 + 73728 + 1728);
    qwfc2[i4] = sgnf(wfc2[i4]);
  }
}

// ---------- conv1 fused: conv + BN1 stats (pre-pool) + 2x2 pool-max -> p1raw ----------
// p1raw[1024][256px][64c] holds max4(conv)*alpha as bf16; BN1 affine+ReLU is applied by
// conv2m's staging (exact: scale>0). Stats are over all pre-pool conv*alpha values.
// __launch_bounds__(256) with NO min-waves arg: (256,4) or no-bounds both force a 64-VGPR
// cap -> ~400 MB scratch spills (R5/R6 FETCH evidence). R4 showed (256) alone -> 136 VGPR, 0 spill.
__global__ __launch_bounds__(256) void k_conv1f(const float* __restrict__ x, const float* __restrict__ qw1t,
                                                const float* __restrict__ absum, u16* __restrict__ p1raw,
                                                float* __restrict__ gs, float* __restrict__ gq){
  __shared__ float xs[3*34*36]; // [ci][y 0..33][x 0..35], data y=1..32, x=2..33
  __shared__ float ls1[64], ls2[64];
  int n = blockIdx.x, t = threadIdx.x;
  if (t < 64){ ls1[t] = 0.f; ls2[t] = 0.f; }
  for (int i = t; i < 3672; i += 256) xs[i] = 0.f;
  __syncthreads();
  const float4* xg = (const float4*)(x + (size_t)n * 3072);
  for (int i = t; i < 768; i += 256){
    float4 v = xg[i];
    int ci = i >> 8, rem = i & 255, y = rem >> 3, xq = (rem & 7) * 4;
    int base = ci*1224 + (y+1)*36 + 2 + xq;
    xs[base+0] = v.x; xs[base+1] = v.y; xs[base+2] = v.z; xs[base+3] = v.w;
  }
  __syncthreads();
  float alpha = absum[0] * (1.f/1728.f);
  int lane = t & 63;
  int oy = t >> 4, ox = t & 15;   // output pixel; quad = input (2oy+sy, 2ox+sx)
  u16x8 pk[8];
  for (int cc = 0; cc < 8; ++cc){
    float acc[4][8];
    #pragma unroll
    for (int s = 0; s < 4; ++s)
      #pragma unroll
      for (int r = 0; r < 8; ++r) acc[s][r] = 0.f;
    for (int ci = 0; ci < 3; ++ci){
      #pragma unroll
      for (int dy = 0; dy < 3; ++dy){
        #pragma unroll
        for (int dx = 0; dx < 3; ++dx){
          int k = ci*9 + dy*3 + dx;
          float wv[8];
          #pragma unroll
          for (int r = 0; r < 8; ++r) wv[r] = qw1t[k*64 + cc*8 + r]; // uniform -> s_load
          #pragma unroll
          for (int s = 0; s < 4; ++s){
            float a = xs[ci*1224 + (2*oy + (s>>1) + dy)*36 + (2*ox + (s&1) + dx + 1)];
            #pragma unroll
            for (int r = 0; r < 8; ++r) acc[s][r] += a * wv[r];
          }
        }
      }
    }
    // fused stats on raw conv values (alpha folded in at the end)
    float s1v[8], s2v[8];
    #pragma unroll
    for (int r = 0; r < 8; ++r){
      s1v[r] = acc[0][r] + acc[1][r] + acc[2][r] + acc[3][r];
      s2v[r] = acc[0][r]*acc[0][r] + acc[1][r]*acc[1][r] + acc[2][r]*acc[2][r] + acc[3][r]*acc[3][r];
    }
    #pragma unroll
    for (int r = 0; r < 8; ++r){
      #pragma unroll
      for (int off = 32; off > 0; off >>= 1){
        s1v[r] += __shfl_xor(s1v[r], off);
        s2v[r] += __shfl_xor(s2v[r], off);
      }
    }
    if (lane == 0){
      #pragma unroll
      for (int r = 0; r < 8; ++r){
        atomicAdd(&ls1[cc*8 + r], s1v[r]);
        atomicAdd(&ls2[cc*8 + r], s2v[r]);
      }
    }
    // pool-max (pre-BN; exact because BN scale > 0)
    #pragma unroll
    for (int r = 0; r < 8; ++r){
      float m = fmaxf(fmaxf(acc[0][r], acc[1][r]), fmaxf(acc[2][r], acc[3][r]));
      pk[cc][r] = f2bf(m * alpha);
    }
  }
  u16* dst = p1raw + ((size_t)n*256 + t)*64;
  #pragma unroll
  for (int cc = 0; cc < 8; ++cc) *(u16x8*)(dst + cc*8) = pk[cc];
  __syncthreads();
  if (t < 64){
    atomicAdd(gs + t, ls1[t] * alpha);
    atomicAdd(gq + t, ls2[t] * alpha * alpha);
  }
}

// ---------- finalize BN affine params ----------
__global__ void k_fin(const float* __restrict__ sum, const float* __restrict__ sumsq,
                      const float* __restrict__ g, const float* __restrict__ b,
                      float* __restrict__ scale, float* __restrict__ bias, int C, float invc){
  int c = blockIdx.x * blockDim.x + threadIdx.x;
  if (c >= C) return;
  float m = sum[c] * invc;
  float var = sumsq[c] * invc - m*m;
  float sc = g[c] * rsqrtf(var + 1e-5f);
  scale[c] = sc;
  bias[c] = b[c] - m * sc;
}

// ---------- conv2 via MFMA, barrier-free K-loop; BN1+ReLU fused into staging ----------
// p1raw[1024][256px][64c] (raw pooled conv1*alpha) -> h2t[1024][256px][128co] bf16.
// Staging applies y = relu(v*sc1+bi1) before writing LDS (bit-identical to old k_bn1 path).
// Fused BN2 stats. Per block: one image. Wave w: rows y = w*4..w*4+3, all 128 co.
__global__ __launch_bounds__(256, 2) void k_conv2m(const u16* __restrict__ p1raw, const u16* __restrict__ qw2b,
                                                   const float* __restrict__ absum,
                                                   const float* __restrict__ sc1, const float* __restrict__ bi1,
                                                   u16* __restrict__ h2t,
                                                   float* __restrict__ gs, float* __restrict__ gq){
  __shared__ __align__(16) u16 img[16384];   // 32 KB, XOR-swizzled 16B units
  __shared__ float ls1[128], ls2[128];
  int n = blockIdx.x, t = threadIdx.x;
  if (t < 128){ ls1[t] = 0.f; ls2[t] = 0.f; }
  // this thread's staged elements are always channels c0..c0+7 (256 % 8 == 0)
  int c0 = (t & 7) * 8;
  float scv[8], biv[8];
  *(float4*)(scv)     = *(const float4*)(sc1 + c0);
  *(float4*)(scv + 4) = *(const float4*)(sc1 + c0 + 4);
  *(float4*)(biv)     = *(const float4*)(bi1 + c0);
  *(float4*)(biv + 4) = *(const float4*)(bi1 + c0 + 4);
  const u16* src = p1raw + (size_t)n * 16384;
  #pragma unroll
  for (int i = 0; i < 8; ++i){
    int id = i*256 + t;            // = px*8 + unit, unit == t&7
    int px = id >> 3, unit = id & 7;
    int su = unit ^ (px & 7);
    u16x8 v = *(const u16x8*)(src + id*8);
    u16x8 o;
    #pragma unroll
    for (int j = 0; j < 8; ++j)
      o[j] = f2bf(fmaxf(bf2f(v[j]) * scv[j] + biv[j], 0.f));
    *(u16x8*)(img + px*64 + su*8) = o;
  }
  __syncthreads();
  int w = t >> 6, lane = t & 63, l15 = lane & 15, q = lane >> 4;
  const s8v* bp = (const s8v*)qw2b;
  f4v acc[4][8];
  #pragma unroll
  for (int a = 0; a < 4; ++a)
    #pragma unroll
    for (int b = 0; b < 8; ++b) acc[a][b] = (f4v)(0.0f);
  for (int dy = 0; dy < 3; ++dy){
    for (int dx = 0; dx < 3; ++dx){
      int s = dy*3 + dx;
      int xv = l15 + dx - 1;
      bool vx = (xv >= 0) && (xv < 16);
      int xc = min(max(xv, 0), 15);
      #pragma unroll
      for (int ks = 0; ks < 2; ++ks){
        s8v bf[8];
        #pragma unroll
        for (int nt = 0; nt < 8; ++nt) bf[nt] = bp[((s*2 + ks)*8 + nt)*64 + lane];
        #pragma unroll
        for (int mt = 0; mt < 4; ++mt){
          int yv = w*4 + mt + dy - 1;
          if (yv < 0 || yv > 15) continue;
          int px = yv*16 + xc;
          int su = (ks*4 + q) ^ (px & 7);
          s8v av = *(const s8v*)(img + px*64 + su*8);
          if (!vx) av = (s8v)(short)0;
          #pragma unroll
          for (int nt = 0; nt < 8; ++nt)
            acc[mt][nt] = __builtin_amdgcn_mfma_f32_16x16x32_bf16(av, bf[nt], acc[mt][nt], 0, 0, 0);
        }
      }
    }
  }
  float alpha = absum[1] * (1.f/73728.f);
  float s1v[8], s2v[8];
  #pragma unroll
  for (int nt = 0; nt < 8; ++nt){ s1v[nt] = 0.f; s2v[nt] = 0.f; }
  #pragma unroll
  for (int mt = 0; mt < 4; ++mt){
    int y = w*4 + mt;
    #pragma unroll
    for (int r = 0; r < 4; ++r){
      int px = y*16 + q*4 + r;
      u16x8 pk;
      #pragma unroll
      for (int nt = 0; nt < 8; ++nt){
        float v = acc[mt][nt][r] * alpha;
        s1v[nt] += v; s2v[nt] += v*v;
        pk[nt] = f2bf(v);
      }
      *(u16x8*)(h2t + ((size_t)n*256 + px)*128 + l15*8) = pk;
    }
  }
  #pragma unroll
  for (int nt = 0; nt < 8; ++nt){
    s1v[nt] += __shfl_xor(s1v[nt], 16); s1v[nt] += __shfl_xor(s1v[nt], 32);
    s2v[nt] += __shfl_xor(s2v[nt], 16); s2v[nt] += __shfl_xor(s2v[nt], 32);
  }
  if (q == 0){
    #pragma unroll
    for (int nt = 0; nt < 8; ++nt){
      atomicAdd(&ls1[l15*8 + nt], s1v[nt]);
      atomicAdd(&ls2[l15*8 + nt], s2v[nt]);
    }
  }
  __syncthreads();
  if (t < 128){ atomicAdd(gs + t, ls1[t]); atomicAdd(gq + t, ls2[t]); }
}

// ---------- BN2+ReLU+pool channel-last: h2t[1024][16x16][128] -> p2[1024][8x8][128] ----------
__global__ __launch_bounds__(256) void k_pool2t(const u16* __restrict__ h2t, u16* __restrict__ p2,
                                                const float* __restrict__ sc, const float* __restrict__ bi){
  __shared__ float lsc[128], lbi[128];
  int n = blockIdx.x, t = threadIdx.x;
  if (t < 128) lsc[t] = sc[t];
  else lbi[t - 128] = bi[t - 128];
  __syncthreads();
  int opx = t >> 2, cq = t & 3;
  int oy = opx >> 3, ox = opx & 7;
  const u16* base = h2t + (size_t)n*32768 + ((oy*2)*16 + ox*2)*128 + cq*32;
  u16* dst = p2 + (size_t)n*8192 + opx*128 + cq*32;
  #pragma unroll
  for (int v = 0; v < 4; ++v){
    u16x8 a0 = *(const u16x8*)(base + v*8);
    u16x8 a1 = *(const u16x8*)(base + 128 + v*8);
    u16x8 a2 = *(const u16x8*)(base + 2048 + v*8);
    u16x8 a3 = *(const u16x8*)(base + 2176 + v*8);
    u16x8 o;
    #pragma unroll
    for (int j = 0; j < 8; ++j){
      int c = cq*32 + v*8 + j;
      float m = fmaxf(fmaxf(bf2f(a0[j]), bf2f(a1[j])), fmaxf(bf2f(a2[j]), bf2f(a3[j])));
      o[j] = f2bf(fmaxf(m * lsc[c] + lbi[c], 0.f));
    }
    *(u16x8*)(dst + v*8) = o;
  }
}

// ---------- fc1 via MFMA, k-split 16: p2[1024][8192] x signs -> h3p[16][1024][256] ----------
__global__ __launch_bounds__(256) void k_fc1m(const u16* __restrict__ p2, const u16* __restrict__ qfc1b,
                                              const float* __restrict__ absum, float* __restrict__ h3p){
  int t = threadIdx.x;
  int bm = blockIdx.x, bn = blockIdx.y, kb = blockIdx.z;
  int w = t >> 6, lane = t & 63, l15 = lane & 15, q = lane >> 4;
  int rowbase = bm*128 + (w >> 1)*64;
  int ntb = bn*8 + (w & 1)*4;
  const s8v* bp = (const s8v*)qfc1b;
  f4v acc[4][4];
  #pragma unroll
  for (int a = 0; a < 4; ++a)
    #pragma unroll
    for (int b = 0; b < 4; ++b) acc[a][b] = (f4v)(0.0f);
  #pragma unroll 2
  for (int ks = 0; ks < 16; ++ks){
    int kst = kb*16 + ks;
    s8v bf[4], af[4];
    #pragma unroll
    for (int nt = 0; nt < 4; ++nt) bf[nt] = bp[(kst*16 + ntb + nt)*64 + lane];
    #pragma unroll
    for (int mt = 0; mt < 4; ++mt)
      af[mt] = *(const s8v*)(p2 + (size_t)(rowbase + mt*16 + l15)*8192 + kst*32 + q*8);
    #pragma unroll
    for (int mt = 0; mt < 4; ++mt)
      #pragma unroll
      for (int nt = 0; nt < 4; ++nt)
        acc[mt][nt] = __builtin_amdgcn_mfma_f32_16x16x32_bf16(af[mt], bf[nt], acc[mt][nt], 0, 0, 0);
  }
  float alpha = absum[2] * (1.f/2097152.f);
  float* dst = h3p + (size_t)kb * 262144;
  #pragma unroll
  for (int mt = 0; mt < 4; ++mt)
    #pragma unroll
    for (int nt = 0; nt < 4; ++nt){
      int col = (ntb + nt)*16 + l15;
      #pragma unroll
      for (int r = 0; r < 4; ++r)
        dst[(size_t)(rowbase + mt*16 + q*4 + r)*256 + col] = acc[mt][nt][r] * alpha;
    }
}

// ---------- reduce k-split slabs + BN3 stats + materialize h3 ----------
__global__ __launch_bounds__(256) void k_fin3f(const float* __restrict__ h3p, float* __restrict__ h3,
                                               float* __restrict__ s3, float* __restrict__ q3){
  int jb = blockIdx.x, ns = blockIdx.y, t = threadIdx.x;
  int jj = t & 31, nn = t >> 5;
  int j = jb*32 + jj;
  float s1 = 0.f, s2 = 0.f;
  for (int i = nn; i < 128; i += 8){
    int n = i*8 + ns;
    float v = 0.f;
    #pragma unroll 8
    for (int kb = 0; kb < 16; ++kb) v += h3p[(size_t)kb*262144 + n*256 + j];
    h3[n*256 + j] = v;
    s1 += v; s2 += v*v;
  }
  __shared__ float l1[256], l2[256];
  l1[t] = s1; l2[t] = s2;
  __syncthreads();
  if (t < 32){
    float a = 0.f, b = 0.f;
    #pragma unroll
    for (int k = 0; k < 8; ++k){ a += l1[t+32*k]; b += l2[t+32*k]; }
    atomicAdd(s3 + jb*32 + t, a); atomicAdd(q3 + jb*32 + t, b);
  }
}

// ---------- fc2: relu(bn3(h3)) @ sign(wfc2)^T -> out[1024,10] fp32 ----------
__global__ __launch_bounds__(64) void k_fc2(const float* __restrict__ h3, const float* __restrict__ qwfc2,
                                            const float* __restrict__ absum, const float* __restrict__ scale,
                                            const float* __restrict__ bias, float* __restrict__ out){
  int n = blockIdx.x, lane = threadIdx.x;
  float a[4];
  #pragma unroll
  for (int i = 0; i < 4; ++i){
    int j = lane + 64*i;
    float v = h3[(size_t)n*256 + j] * scale[j] + bias[j];
    a[i] = fmaxf(v, 0.f);
  }
  float alpha = absum[3] * (1.f/2560.f);
  #pragma unroll
  for (int k = 0; k < 10; ++k){
    float p = 0.f;
    #pragma unroll
    for (int i = 0; i < 4; ++i) p += a[i] * qwfc2[k*256 + lane + 64*i];
    #pragma unroll
    for (int off = 32; off > 0; off >>= 1) p += __shfl_down(p, off);
    if (lane == 0) out[n*10 + k] = p * alpha;
  }
}

extern "C" void kernel_launch(void* const* d_in, const int* in_sizes, int n_in,
                              void* d_out, int out_size, void* d_ws, size_t ws_size,
                              hipStream_t stream){
  (void)in_sizes; (void)n_in; (void)out_size; (void)ws_size;
  const float* x    = (const float*)d_in[0];
  const float* w1   = (const float*)d_in[1];
  const float* g1   = (const float*)d_in[2];
  const float* b1   = (const float*)d_in[3];
  const float* w2   = (const float*)d_in[4];
  const float* g2   = (const float*)d_in[5];
  const float* b2   = (const float*)d_in[6];
  const float* wfc1 = (const float*)d_in[7];
  const float* g3   = (const float*)d_in[8];
  const float* b3   = (const float*)d_in[9];
  const float* wfc2 = (const float*)d_in[10];
  float* out = (float*)d_out;

  float* wsf = (float*)d_ws;
  char*  wsb = (char*)d_ws;
  float* absum = wsf;
  float* s1 = wsf + 16;   float* q1 = wsf + 80;
  float* s2 = wsf + 144;  float* q2 = wsf + 272;
  float* s3 = wsf + 1024; float* q3 = wsf + 1280;
  float* sc1 = wsf + 1536; float* bi1 = wsf + 1600;
  float* sc2 = wsf + 1664; float* bi2 = wsf + 1792;
  float* sc3 = wsf + 2048; float* bi3 = wsf + 2304;
  float* qw1t  = wsf + 4096;                         // 1728 fp32
  u16*   qw2b  = (u16*)(wsb + (64u << 10));          // 144 KB bf16 B-frags
  float* qwfc2 = (float*)(wsb + (256u << 10));       // 10 KB fp32
  float* h3    = (float*)(wsb + (1ull << 20));       // 1 MB fp32 [1024][256]
  u16*   qfc1b = (u16*)(wsb + (2ull << 20));         // 4 MB bf16 B-frags
  u16*   p1t   = (u16*)(wsb + (8ull << 20) + 4096);  // 32 MB bf16 [1024][256][64]
  u16*   h2t   = (u16*)(wsb + (48ull << 20));        // 64 MB bf16 [1024][256][128]
  u16*   p2    = (u16*)(wsb + (112ull << 20));       // 16 MB bf16 [1024][8192] (channel-last k)
  float* h3p   = (float*)(wsb + (128ull << 20));     // 16 MB fp32 [16][1024][256]

  k_zero<<<10, 256, 0, stream>>>(wsf, 2560);
  k_absum<<<98, 256, 0, stream>>>(w1, w2, wfc1, wfc2, absum);
  k_signgen<<<8498, 256, 0, stream>>>(w1, w2, wfc1, wfc2, qw1t, qw2b, qfc1b, qwfc2);
  k_conv1f<<<1024, 256, 0, stream>>>(x, qw1t, absum, p1t, s1, q1);
  k_fin<<<1, 64, 0, stream>>>(s1, q1, g1, b1, sc1, bi1, 64, 1.f/1048576.f);
  k_conv2m<<<1024, 256, 0, stream>>>(p1t, qw2b, absum, sc1, bi1, h2t, s2, q2);
  k_fin<<<1, 128, 0, stream>>>(s2, q2, g2, b2, sc2, bi2, 128, 1.f/262144.f);
  k_pool2t<<<1024, 256, 0, stream>>>(h2t, p2, sc2, bi2);
  k_fc1m<<<dim3(8, 2, 16), 256, 0, stream>>>(p2, qfc1b, absum, h3p);
  k_fin3f<<<dim3(8, 8), 256, 0, stream>>>(h3p, h3, s3, q3);
  k_fin<<<1, 256, 0, stream>>>(s3, q3, g3, b3, sc3, bi3, 256, 1.f/1024.f);
  k_fc2<<<1024, 64, 0, stream>>>(h3, qwfc2, absum, sc3, bi3, out);
}

// Round 8
// 340.647 us; speedup vs baseline: 2.8897x; 2.8897x over previous
//
#include <hip/hip_runtime.h>
#include <stdint.h>

typedef unsigned short u16;
typedef unsigned int u32;
typedef __attribute__((ext_vector_type(8))) short s8v;   // 8 bf16 = 4 VGPR (MFMA A/B frag)
typedef __attribute__((ext_vector_type(4))) float f4v;   // MFMA C/D frag
typedef __attribute__((ext_vector_type(8))) u16 u16x8;

// ---------- bf16 helpers ----------
__device__ __forceinline__ float bf2f(u16 u){
  union { u32 i; float f; } v; v.i = ((u32)u) << 16; return v.f;
}
__device__ __forceinline__ u16 f2bf(float f){
  union { float f; u32 i; } v; v.f = f;
  u32 i = v.i;
  return (u16)((i + 0x7fffu + ((i >> 16) & 1u)) >> 16); // RNE
}
__device__ __forceinline__ float sgnf(float w){
  return (w > 0.f) ? 1.f : ((w < 0.f) ? -1.f : 0.f);
}
__device__ __forceinline__ u16 sgn_bf(float w){
  return (w > 0.f) ? (u16)0x3F80 : ((w < 0.f) ? (u16)0xBF80 : (u16)0);
}

// ---------- block reduction (256 threads = 4 waves) ----------
__device__ __forceinline__ void block_reduce2(float& a, float& b){
  #pragma unroll
  for (int off = 32; off > 0; off >>= 1){
    a += __shfl_down(a, off);
    b += __shfl_down(b, off);
  }
  __shared__ float ra[4], rb[4];
  int lane = threadIdx.x & 63, w = threadIdx.x >> 6;
  __syncthreads();
  if (lane == 0){ ra[w] = a; rb[w] = b; }
  __syncthreads();
  if (threadIdx.x == 0){
    a = ra[0] + ra[1] + ra[2] + ra[3];
    b = rb[0] + rb[1] + rb[2] + rb[3];
  }
}

__global__ void k_zero(float* __restrict__ p, int n){
  int i = blockIdx.x * blockDim.x + threadIdx.x;
  if (i < n) p[i] = 0.f;
}

// ---------- sum(|w|) for the 4 weight tensors ----------
__global__ __launch_bounds__(256) void k_absum(const float* __restrict__ w1, const float* __restrict__ w2,
                                               const float* __restrict__ wfc1, const float* __restrict__ wfc2,
                                               float* __restrict__ absum){
  int b = blockIdx.x, t = threadIdx.x;
  const float* src; int n0, cnt, slot;
  if (b < 64)      { src = wfc1; slot = 2; cnt = 2097152/64; n0 = b * cnt; }
  else if (b < 96) { src = w2;   slot = 1; cnt = 73728/32;   n0 = (b-64) * cnt; }
  else if (b == 96){ src = w1;   slot = 0; cnt = 1728;       n0 = 0; }
  else             { src = wfc2; slot = 3; cnt = 2560;       n0 = 0; }
  float s = 0.f, d = 0.f;
  for (int i = t; i < cnt; i += 256) s += fabsf(src[n0 + i]);
  block_reduce2(s, d);
  if (t == 0) atomicAdd(absum + slot, s);
}

// ---------- generate all quantized weight forms ----------
// qw1t: fp32 [27 k][64 co] for conv1 VALU
// qw2b: bf16 MFMA B-frags for conv2, frag fid=(s*2+ks)*8+nt, elem idx=fid*512+lane*8+j
//       co = (lane&15)*8 + nt   (co permutation -> coalesced channel-last stores)
//       c  = ks*32 + (lane>>4)*8 + j
// qfc1b: bf16 MFMA B-frags for fc1, frag = kstep*16+nt; k_phys = kstep*32+(lane>>4)*8+j
//       p2 is channel-last: k_phys = px*128+c  ->  logical k = c*64+px
// qwfc2: fp32 sign [10][256]
__global__ __launch_bounds__(256) void k_signgen(const float* __restrict__ w1, const float* __restrict__ w2,
                                                 const float* __restrict__ wfc1, const float* __restrict__ wfc2,
                                                 float* __restrict__ qw1t, u16* __restrict__ qw2b,
                                                 u16* __restrict__ qfc1b, float* __restrict__ qwfc2){
  int i = blockIdx.x * 256 + threadIdx.x;
  if (i < 2097152){
    int j = i & 7, lane = (i >> 3) & 63, fid = i >> 9;
    int kstep = fid >> 4, nt = fid & 15;
    int co = nt*16 + (lane & 15);
    int k_phys = kstep*32 + (lane >> 4)*8 + j;
    int px = k_phys >> 7, c = k_phys & 127;
    qfc1b[i] = sgn_bf(wfc1[(size_t)co*8192 + c*64 + px]);
  } else if (i < 2097152 + 73728){
    int i2 = i - 2097152;
    int j = i2 & 7, lane = (i2 >> 3) & 63, fid = i2 >> 9;  // 0..143
    int s = fid >> 4, ks = (fid >> 3) & 1, nt = fid & 7;
    int co = (lane & 15)*8 + nt;
    int c = ks*32 + (lane >> 4)*8 + j;
    qw2b[i2] = sgn_bf(w2[((size_t)co*64 + c)*9 + s]);
  } else if (i < 2097152 + 73728 + 1728){
    int i3 = i - (2097152 + 73728);
    int co = i3 / 27, k = i3 % 27;
    qw1t[k*64 + co] = sgnf(w1[i3]);
  } else if (i < 2097152 + 73728 + 1728 + 2560){
    int i4 = i - (2097152 + 73728 + 1728);
    qwfc2[i4] = sgnf(wfc2[i4]);
  }
}

// ---------- conv1 fused: conv + BN1 stats (pre-pool) + 2x2 pool-max -> p1raw ----------
// p1raw[1024][256px][64c] holds max4(conv)*alpha as bf16; BN1 affine+ReLU is applied by
// conv2m's staging (exact: scale>0). Stats over all pre-pool conv*alpha values.
// REGISTER-PRESSURE NOTE (R7 post-mortem): buffering acc[4][8]+pk[8] across the cc loop
// put the allocator exactly at the 128-VGPR boundary -> live-range-split/remat code bloat
// (761 us at VALUBusy 78%, 25x the FMA stream). This version keeps only pm/s1v/s2v/a8
// (32 floats) live: quad index s is OUTER, conv acc a8[] is per-s and dies immediately.
__global__ __launch_bounds__(256) void k_conv1f(const float* __restrict__ x, const float* __restrict__ qw1t,
                                                const float* __restrict__ absum, u16* __restrict__ p1raw,
                                                float* __restrict__ gs, float* __restrict__ gq){
  __shared__ float xs[3*34*36]; // [ci][y 0..33][x 0..35], data y=1..32, x=2..33
  __shared__ float ls1[64], ls2[64];
  int n = blockIdx.x, t = threadIdx.x;
  if (t < 64){ ls1[t] = 0.f; ls2[t] = 0.f; }
  for (int i = t; i < 3672; i += 256) xs[i] = 0.f;
  __syncthreads();
  const float4* xg = (const float4*)(x + (size_t)n * 3072);
  for (int i = t; i < 768; i += 256){
    float4 v = xg[i];
    int ci = i >> 8, rem = i & 255, y = rem >> 3, xq = (rem & 7) * 4;
    int base = ci*1224 + (y+1)*36 + 2 + xq;
    xs[base+0] = v.x; xs[base+1] = v.y; xs[base+2] = v.z; xs[base+3] = v.w;
  }
  __syncthreads();
  float alpha = absum[0] * (1.f/1728.f);
  int lane = t & 63;
  int oy = t >> 4, ox = t & 15;             // output (pooled) pixel
  const float* xq0 = xs + (2*oy)*36 + 2*ox; // all further offsets compile-time imm
  u16* dst = p1raw + ((size_t)n*256 + t)*64;
  for (int cc = 0; cc < 8; ++cc){           // NOT unrolled: keeps live state small
    float pm[8], s1v[8], s2v[8];
    #pragma unroll
    for (int s = 0; s < 4; ++s){
      float a8[8];
      #pragma unroll
      for (int r = 0; r < 8; ++r) a8[r] = 0.f;
      #pragma unroll
      for (int ci = 0; ci < 3; ++ci){
        #pragma unroll
        for (int dy = 0; dy < 3; ++dy){
          #pragma unroll
          for (int dx = 0; dx < 3; ++dx){
            int k = ci*9 + dy*3 + dx;
            float wv[8];
            #pragma unroll
            for (int r = 0; r < 8; ++r) wv[r] = qw1t[k*64 + cc*8 + r]; // uniform -> s_load
            float a = xq0[ci*1224 + ((s>>1) + dy)*36 + ((s&1) + dx + 1)];
            #pragma unroll
            for (int r = 0; r < 8; ++r) a8[r] += a * wv[r];
          }
        }
      }
      if (s == 0){
        #pragma unroll
        for (int r = 0; r < 8; ++r){ pm[r] = a8[r]; s1v[r] = a8[r]; s2v[r] = a8[r]*a8[r]; }
      } else {
        #pragma unroll
        for (int r = 0; r < 8; ++r){
          pm[r] = fmaxf(pm[r], a8[r]);
          s1v[r] += a8[r]; s2v[r] += a8[r]*a8[r];
        }
      }
    }
    // wave butterfly then one LDS atomic per channel
    #pragma unroll
    for (int r = 0; r < 8; ++r){
      #pragma unroll
      for (int off = 32; off > 0; off >>= 1){
        s1v[r] += __shfl_xor(s1v[r], off);
        s2v[r] += __shfl_xor(s2v[r], off);
      }
    }
    if (lane == 0){
      #pragma unroll
      for (int r = 0; r < 8; ++r){
        atomicAdd(&ls1[cc*8 + r], s1v[r]);
        atomicAdd(&ls2[cc*8 + r], s2v[r]);
      }
    }
    // pooled store (pre-BN; exact because BN scale > 0). 16B per cc; the 8 cc stores
    // fill this thread's 128B run contiguously (R7 measured WRITE=33MB ideal).
    u16x8 pk;
    #pragma unroll
    for (int r = 0; r < 8; ++r) pk[r] = f2bf(pm[r] * alpha);
    *(u16x8*)(dst + cc*8) = pk;
  }
  __syncthreads();
  if (t < 64){
    atomicAdd(gs + t, ls1[t] * alpha);
    atomicAdd(gq + t, ls2[t] * alpha * alpha);
  }
}

// ---------- finalize BN affine params ----------
__global__ void k_fin(const float* __restrict__ sum, const float* __restrict__ sumsq,
                      const float* __restrict__ g, const float* __restrict__ b,
                      float* __restrict__ scale, float* __restrict__ bias, int C, float invc){
  int c = blockIdx.x * blockDim.x + threadIdx.x;
  if (c >= C) return;
  float m = sum[c] * invc;
  float var = sumsq[c] * invc - m*m;
  float sc = g[c] * rsqrtf(var + 1e-5f);
  scale[c] = sc;
  bias[c] = b[c] - m * sc;
}

// ---------- conv2 via MFMA, barrier-free K-loop; BN1+ReLU fused into staging ----------
// p1raw[1024][256px][64c] (raw pooled conv1*alpha) -> h2t[1024][256px][128co] bf16.
// Staging applies y = relu(v*sc1+bi1) before writing LDS. Fused BN2 stats.
// Per block: one image. Wave w: rows y = w*4..w*4+3, all 128 co.
__global__ __launch_bounds__(256, 2) void k_conv2m(const u16* __restrict__ p1raw, const u16* __restrict__ qw2b,
                                                   const float* __restrict__ absum,
                                                   const float* __restrict__ sc1, const float* __restrict__ bi1,
                                                   u16* __restrict__ h2t,
                                                   float* __restrict__ gs, float* __restrict__ gq){
  __shared__ __align__(16) u16 img[16384];   // 32 KB, XOR-swizzled 16B units
  __shared__ float ls1[128], ls2[128];
  int n = blockIdx.x, t = threadIdx.x;
  if (t < 128){ ls1[t] = 0.f; ls2[t] = 0.f; }
  // this thread's staged elements are always channels c0..c0+7 (256 % 8 == 0)
  int c0 = (t & 7) * 8;
  float scv[8], biv[8];
  *(float4*)(scv)     = *(const float4*)(sc1 + c0);
  *(float4*)(scv + 4) = *(const float4*)(sc1 + c0 + 4);
  *(float4*)(biv)     = *(const float4*)(bi1 + c0);
  *(float4*)(biv + 4) = *(const float4*)(bi1 + c0 + 4);
  const u16* src = p1raw + (size_t)n * 16384;
  #pragma unroll
  for (int i = 0; i < 8; ++i){
    int id = i*256 + t;            // = px*8 + unit, unit == t&7
    int px = id >> 3, unit = id & 7;
    int su = unit ^ (px & 7);
    u16x8 v = *(const u16x8*)(src + id*8);
    u16x8 o;
    #pragma unroll
    for (int j = 0; j < 8; ++j)
      o[j] = f2bf(fmaxf(bf2f(v[j]) * scv[j] + biv[j], 0.f));
    *(u16x8*)(img + px*64 + su*8) = o;
  }
  __syncthreads();
  int w = t >> 6, lane = t & 63, l15 = lane & 15, q = lane >> 4;
  const s8v* bp = (const s8v*)qw2b;
  f4v acc[4][8];
  #pragma unroll
  for (int a = 0; a < 4; ++a)
    #pragma unroll
    for (int b = 0; b < 8; ++b) acc[a][b] = (f4v)(0.0f);
  for (int dy = 0; dy < 3; ++dy){
    for (int dx = 0; dx < 3; ++dx){
      int s = dy*3 + dx;
      int xv = l15 + dx - 1;
      bool vx = (xv >= 0) && (xv < 16);
      int xc = min(max(xv, 0), 15);
      #pragma unroll
      for (int ks = 0; ks < 2; ++ks){
        s8v bf[8];
        #pragma unroll
        for (int nt = 0; nt < 8; ++nt) bf[nt] = bp[((s*2 + ks)*8 + nt)*64 + lane];
        #pragma unroll
        for (int mt = 0; mt < 4; ++mt){
          int yv = w*4 + mt + dy - 1;
          if (yv < 0 || yv > 15) continue;
          int px = yv*16 + xc;
          int su = (ks*4 + q) ^ (px & 7);
          s8v av = *(const s8v*)(img + px*64 + su*8);
          if (!vx) av = (s8v)(short)0;
          #pragma unroll
          for (int nt = 0; nt < 8; ++nt)
            acc[mt][nt] = __builtin_amdgcn_mfma_f32_16x16x32_bf16(av, bf[nt], acc[mt][nt], 0, 0, 0);
        }
      }
    }
  }
  float alpha = absum[1] * (1.f/73728.f);
  float s1v[8], s2v[8];
  #pragma unroll
  for (int nt = 0; nt < 8; ++nt){ s1v[nt] = 0.f; s2v[nt] = 0.f; }
  #pragma unroll
  for (int mt = 0; mt < 4; ++mt){
    int y = w*4 + mt;
    #pragma unroll
    for (int r = 0; r < 4; ++r){
      int px = y*16 + q*4 + r;
      u16x8 pk;
      #pragma unroll
      for (int nt = 0; nt < 8; ++nt){
        float v = acc[mt][nt][r] * alpha;
        s1v[nt] += v; s2v[nt] += v*v;
        pk[nt] = f2bf(v);
      }
      *(u16x8*)(h2t + ((size_t)n*256 + px)*128 + l15*8) = pk;
    }
  }
  #pragma unroll
  for (int nt = 0; nt < 8; ++nt){
    s1v[nt] += __shfl_xor(s1v[nt], 16); s1v[nt] += __shfl_xor(s1v[nt], 32);
    s2v[nt] += __shfl_xor(s2v[nt], 16); s2v[nt] += __shfl_xor(s2v[nt], 32);
  }
  if (q == 0){
    #pragma unroll
    for (int nt = 0; nt < 8; ++nt){
      atomicAdd(&ls1[l15*8 + nt], s1v[nt]);
      atomicAdd(&ls2[l15*8 + nt], s2v[nt]);
    }
  }
  __syncthreads();
  if (t < 128){ atomicAdd(gs + t, ls1[t]); atomicAdd(gq + t, ls2[t]); }
}

// ---------- BN2+ReLU+pool channel-last: h2t[1024][16x16][128] -> p2[1024][8x8][128] ----------
__global__ __launch_bounds__(256) void k_pool2t(const u16* __restrict__ h2t, u16* __restrict__ p2,
                                                const float* __restrict__ sc, const float* __restrict__ bi){
  __shared__ float lsc[128], lbi[128];
  int n = blockIdx.x, t = threadIdx.x;
  if (t < 128) lsc[t] = sc[t];
  else lbi[t - 128] = bi[t - 128];
  __syncthreads();
  int opx = t >> 2, cq = t & 3;
  int oy = opx >> 3, ox = opx & 7;
  const u16* base = h2t + (size_t)n*32768 + ((oy*2)*16 + ox*2)*128 + cq*32;
  u16* dst = p2 + (size_t)n*8192 + opx*128 + cq*32;
  #pragma unroll
  for (int v = 0; v < 4; ++v){
    u16x8 a0 = *(const u16x8*)(base + v*8);
    u16x8 a1 = *(const u16x8*)(base + 128 + v*8);
    u16x8 a2 = *(const u16x8*)(base + 2048 + v*8);
    u16x8 a3 = *(const u16x8*)(base + 2176 + v*8);
    u16x8 o;
    #pragma unroll
    for (int j = 0; j < 8; ++j){
      int c = cq*32 + v*8 + j;
      float m = fmaxf(fmaxf(bf2f(a0[j]), bf2f(a1[j])), fmaxf(bf2f(a2[j]), bf2f(a3[j])));
      o[j] = f2bf(fmaxf(m * lsc[c] + lbi[c], 0.f));
    }
    *(u16x8*)(dst + v*8) = o;
  }
}

// ---------- fc1 via MFMA, k-split 16: p2[1024][8192] x signs -> h3p[16][1024][256] ----------
__global__ __launch_bounds__(256) void k_fc1m(const u16* __restrict__ p2, const u16* __restrict__ qfc1b,
                                              const float* __restrict__ absum, float* __restrict__ h3p){
  int t = threadIdx.x;
  int bm = blockIdx.x, bn = blockIdx.y, kb = blockIdx.z;
  int w = t >> 6, lane = t & 63, l15 = lane & 15, q = lane >> 4;
  int rowbase = bm*128 + (w >> 1)*64;
  int ntb = bn*8 + (w & 1)*4;
  const s8v* bp = (const s8v*)qfc1b;
  f4v acc[4][4];
  #pragma unroll
  for (int a = 0; a < 4; ++a)
    #pragma unroll
    for (int b = 0; b < 4; ++b) acc[a][b] = (f4v)(0.0f);
  #pragma unroll 2
  for (int ks = 0; ks < 16; ++ks){
    int kst = kb*16 + ks;
    s8v bf[4], af[4];
    #pragma unroll
    for (int nt = 0; nt < 4; ++nt) bf[nt] = bp[(kst*16 + ntb + nt)*64 + lane];
    #pragma unroll
    for (int mt = 0; mt < 4; ++mt)
      af[mt] = *(const s8v*)(p2 + (size_t)(rowbase + mt*16 + l15)*8192 + kst*32 + q*8);
    #pragma unroll
    for (int mt = 0; mt < 4; ++mt)
      #pragma unroll
      for (int nt = 0; nt < 4; ++nt)
        acc[mt][nt] = __builtin_amdgcn_mfma_f32_16x16x32_bf16(af[mt], bf[nt], acc[mt][nt], 0, 0, 0);
  }
  float alpha = absum[2] * (1.f/2097152.f);
  float* dst = h3p + (size_t)kb * 262144;
  #pragma unroll
  for (int mt = 0; mt < 4; ++mt)
    #pragma unroll
    for (int nt = 0; nt < 4; ++nt){
      int col = (ntb + nt)*16 + l15;
      #pragma unroll
      for (int r = 0; r < 4; ++r)
        dst[(size_t)(rowbase + mt*16 + q*4 + r)*256 + col] = acc[mt][nt][r] * alpha;
    }
}

// ---------- reduce k-split slabs + BN3 stats + materialize h3 ----------
__global__ __launch_bounds__(256) void k_fin3f(const float* __restrict__ h3p, float* __restrict__ h3,
                                               float* __restrict__ s3, float* __restrict__ q3){
  int jb = blockIdx.x, ns = blockIdx.y, t = threadIdx.x;
  int jj = t & 31, nn = t >> 5;
  int j = jb*32 + jj;
  float s1 = 0.f, s2 = 0.f;
  for (int i = nn; i < 128; i += 8){
    int n = i*8 + ns;
    float v = 0.f;
    #pragma unroll 8
    for (int kb = 0; kb < 16; ++kb) v += h3p[(size_t)kb*262144 + n*256 + j];
    h3[n*256 + j] = v;
    s1 += v; s2 += v*v;
  }
  __shared__ float l1[256], l2[256];
  l1[t] = s1; l2[t] = s2;
  __syncthreads();
  if (t < 32){
    float a = 0.f, b = 0.f;
    #pragma unroll
    for (int k = 0; k < 8; ++k){ a += l1[t+32*k]; b += l2[t+32*k]; }
    atomicAdd(s3 + jb*32 + t, a); atomicAdd(q3 + jb*32 + t, b);
  }
}

// ---------- fc2: relu(bn3(h3)) @ sign(wfc2)^T -> out[1024,10] fp32 ----------
__global__ __launch_bounds__(64) void k_fc2(const float* __restrict__ h3, const float* __restrict__ qwfc2,
                                            const float* __restrict__ absum, const float* __restrict__ scale,
                                            const float* __restrict__ bias, float* __restrict__ out){
  int n = blockIdx.x, lane = threadIdx.x;
  float a[4];
  #pragma unroll
  for (int i = 0; i < 4; ++i){
    int j = lane + 64*i;
    float v = h3[(size_t)n*256 + j] * scale[j] + bias[j];
    a[i] = fmaxf(v, 0.f);
  }
  float alpha = absum[3] * (1.f/2560.f);
  #pragma unroll
  for (int k = 0; k < 10; ++k){
    float p = 0.f;
    #pragma unroll
    for (int i = 0; i < 4; ++i) p += a[i] * qwfc2[k*256 + lane + 64*i];
    #pragma unroll
    for (int off = 32; off > 0; off >>= 1) p += __shfl_down(p, off);
    if (lane == 0) out[n*10 + k] = p * alpha;
  }
}

extern "C" void kernel_launch(void* const* d_in, const int* in_sizes, int n_in,
                              void* d_out, int out_size, void* d_ws, size_t ws_size,
                              hipStream_t stream){
  (void)in_sizes; (void)n_in; (void)out_size; (void)ws_size;
  const float* x    = (const float*)d_in[0];
  const float* w1   = (const float*)d_in[1];
  const float* g1   = (const float*)d_in[2];
  const float* b1   = (const float*)d_in[3];
  const float* w2   = (const float*)d_in[4];
  const float* g2   = (const float*)d_in[5];
  const float* b2   = (const float*)d_in[6];
  const float* wfc1 = (const float*)d_in[7];
  const float* g3   = (const float*)d_in[8];
  const float* b3   = (const float*)d_in[9];
  const float* wfc2 = (const float*)d_in[10];
  float* out = (float*)d_out;

  float* wsf = (float*)d_ws;
  char*  wsb = (char*)d_ws;
  float* absum = wsf;
  float* s1 = wsf + 16;   float* q1 = wsf + 80;
  float* s2 = wsf + 144;  float* q2 = wsf + 272;
  float* s3 = wsf + 1024; float* q3 = wsf + 1280;
  float* sc1 = wsf + 1536; float* bi1 = wsf + 1600;
  float* sc2 = wsf + 1664; float* bi2 = wsf + 1792;
  float* sc3 = wsf + 2048; float* bi3 = wsf + 2304;
  float* qw1t  = wsf + 4096;                         // 1728 fp32
  u16*   qw2b  = (u16*)(wsb + (64u << 10));          // 144 KB bf16 B-frags
  float* qwfc2 = (float*)(wsb + (256u << 10));       // 10 KB fp32
  float* h3    = (float*)(wsb + (1ull << 20));       // 1 MB fp32 [1024][256]
  u16*   qfc1b = (u16*)(wsb + (2ull << 20));         // 4 MB bf16 B-frags
  u16*   p1t   = (u16*)(wsb + (8ull << 20) + 4096);  // 32 MB bf16 [1024][256][64]
  u16*   h2t   = (u16*)(wsb + (48ull << 20));        // 64 MB bf16 [1024][256][128]
  u16*   p2    = (u16*)(wsb + (112ull << 20));       // 16 MB bf16 [1024][8192] (channel-last k)
  float* h3p   = (float*)(wsb + (128ull << 20));     // 16 MB fp32 [16][1024][256]

  k_zero<<<10, 256, 0, stream>>>(wsf, 2560);
  k_absum<<<98, 256, 0, stream>>>(w1, w2, wfc1, wfc2, absum);
  k_signgen<<<8498, 256, 0, stream>>>(w1, w2, wfc1, wfc2, qw1t, qw2b, qfc1b, qwfc2);
  k_conv1f<<<1024, 256, 0, stream>>>(x, qw1t, absum, p1t, s1, q1);
  k_fin<<<1, 64, 0, stream>>>(s1, q1, g1, b1, sc1, bi1, 64, 1.f/1048576.f);
  k_conv2m<<<1024, 256, 0, stream>>>(p1t, qw2b, absum, sc1, bi1, h2t, s2, q2);
  k_fin<<<1, 128, 0, stream>>>(s2, q2, g2, b2, sc2, bi2, 128, 1.f/262144.f);
  k_pool2t<<<1024, 256, 0, stream>>>(h2t, p2, sc2, bi2);
  k_fc1m<<<dim3(8, 2, 16), 256, 0, stream>>>(p2, qfc1b, absum, h3p);
  k_fin3f<<<dim3(8, 8), 256, 0, stream>>>(h3p, h3, s3, q3);
  k_fin<<<1, 256, 0, stream>>>(s3, q3, g3, b3, sc3, bi3, 256, 1.f/1024.f);
  k_fc2<<<1024, 64, 0, stream>>>(h3, qwfc2, absum, sc3, bi3, out);
}

// Round 9
// 296.575 us; speedup vs baseline: 3.3191x; 1.1486x over previous
//
#include <hip/hip_runtime.h>
#include <stdint.h>

typedef unsigned short u16;
typedef unsigned int u32;
typedef __attribute__((ext_vector_type(8))) short s8v;   // 8 bf16 = 4 VGPR (MFMA A/B frag)
typedef __attribute__((ext_vector_type(4))) float f4v;   // MFMA C/D frag
typedef __attribute__((ext_vector_type(8))) u16 u16x8;

// ---------- bf16 helpers ----------
__device__ __forceinline__ float bf2f(u16 u){
  union { u32 i; float f; } v; v.i = ((u32)u) << 16; return v.f;
}
__device__ __forceinline__ u16 f2bf(float f){
  union { float f; u32 i; } v; v.f = f;
  u32 i = v.i;
  return (u16)((i + 0x7fffu + ((i >> 16) & 1u)) >> 16); // RNE
}
__device__ __forceinline__ float sgnf(float w){
  return (w > 0.f) ? 1.f : ((w < 0.f) ? -1.f : 0.f);
}
__device__ __forceinline__ u16 sgn_bf(float w){
  return (w > 0.f) ? (u16)0x3F80 : ((w < 0.f) ? (u16)0xBF80 : (u16)0);
}

// ---------- block reduction (256 threads = 4 waves) ----------
__device__ __forceinline__ void block_reduce2(float& a, float& b){
  #pragma unroll
  for (int off = 32; off > 0; off >>= 1){
    a += __shfl_down(a, off);
    b += __shfl_down(b, off);
  }
  __shared__ float ra[4], rb[4];
  int lane = threadIdx.x & 63, w = threadIdx.x >> 6;
  __syncthreads();
  if (lane == 0){ ra[w] = a; rb[w] = b; }
  __syncthreads();
  if (threadIdx.x == 0){
    a = ra[0] + ra[1] + ra[2] + ra[3];
    b = rb[0] + rb[1] + rb[2] + rb[3];
  }
}

__global__ void k_zero(float* __restrict__ p, int n){
  int i = blockIdx.x * blockDim.x + threadIdx.x;
  if (i < n) p[i] = 0.f;
}

// ---------- sum(|w|) for the 4 weight tensors ----------
__global__ __launch_bounds__(256) void k_absum(const float* __restrict__ w1, const float* __restrict__ w2,
                                               const float* __restrict__ wfc1, const float* __restrict__ wfc2,
                                               float* __restrict__ absum){
  int b = blockIdx.x, t = threadIdx.x;
  const float* src; int n0, cnt, slot;
  if (b < 64)      { src = wfc1; slot = 2; cnt = 2097152/64; n0 = b * cnt; }
  else if (b < 96) { src = w2;   slot = 1; cnt = 73728/32;   n0 = (b-64) * cnt; }
  else if (b == 96){ src = w1;   slot = 0; cnt = 1728;       n0 = 0; }
  else             { src = wfc2; slot = 3; cnt = 2560;       n0 = 0; }
  float s = 0.f, d = 0.f;
  for (int i = t; i < cnt; i += 256) s += fabsf(src[n0 + i]);
  block_reduce2(s, d);
  if (t == 0) atomicAdd(absum + slot, s);
}

// ---------- generate all quantized weight forms ----------
// qw1b: bf16 MFMA B-frags for conv1, frag nt (4): co = nt*16+(lane&15),
//       k = (lane>>4)*8+j, k<27 -> sign(w1[co*27+k]) else 0   (2048 u16)
// qw2b: bf16 MFMA B-frags for conv2 (co = (lane&15)*8+nt permutation)
// qfc1b: bf16 MFMA B-frags for fc1 (k permuted for channel-last p2)
// qwfc2: fp32 sign [10][256]
__global__ __launch_bounds__(256) void k_signgen(const float* __restrict__ w1, const float* __restrict__ w2,
                                                 const float* __restrict__ wfc1, const float* __restrict__ wfc2,
                                                 u16* __restrict__ qw1b, u16* __restrict__ qw2b,
                                                 u16* __restrict__ qfc1b, float* __restrict__ qwfc2){
  int i = blockIdx.x * 256 + threadIdx.x;
  if (i < 2097152){
    int j = i & 7, lane = (i >> 3) & 63, fid = i >> 9;
    int kstep = fid >> 4, nt = fid & 15;
    int co = nt*16 + (lane & 15);
    int k_phys = kstep*32 + (lane >> 4)*8 + j;
    int px = k_phys >> 7, c = k_phys & 127;
    qfc1b[i] = sgn_bf(wfc1[(size_t)co*8192 + c*64 + px]);
  } else if (i < 2097152 + 73728){
    int i2 = i - 2097152;
    int j = i2 & 7, lane = (i2 >> 3) & 63, fid = i2 >> 9;  // 0..143
    int s = fid >> 4, ks = (fid >> 3) & 1, nt = fid & 7;
    int co = (lane & 15)*8 + nt;
    int c = ks*32 + (lane >> 4)*8 + j;
    qw2b[i2] = sgn_bf(w2[((size_t)co*64 + c)*9 + s]);
  } else if (i < 2097152 + 73728 + 2048){
    int i3 = i - (2097152 + 73728);
    int j = i3 & 7, lane = (i3 >> 3) & 63, nt = i3 >> 9;   // 0..3
    int co = nt*16 + (lane & 15);
    int k = (lane >> 4)*8 + j;
    qw1b[i3] = (k < 27) ? sgn_bf(w1[co*27 + k]) : (u16)0;
  } else if (i < 2097152 + 73728 + 2048 + 2560){
    int i4 = i - (2097152 + 73728 + 2048);
    qwfc2[i4] = sgnf(wfc2[i4]);
  }
}

// ---------- conv1 via MFMA: im2col in LDS + fused BN1 stats + in-lane 2x2 pool ----------
// x[1024,3,32,32] fp32 -> p1raw[1024][256 pooled px][64c] bf16 (= max4(conv)*alpha).
// im2col row m = pooled_group*4 + member, so MFMA C rows (q*4+reg) put the 4 pool members
// of group g = tile*4+q in one lane's 4 regs: pool = 3 v_max, no cross-lane.
// Stats (pre-pool, exact) = in-lane sums + shfl_xor(16,32) + LDS atomics.
// K = 27 padded to 32 -> one 16x16x32 MFMA per (tile, co-tile). A rows 80B stride (2-way max).
__global__ __launch_bounds__(256) void k_conv1m(const float* __restrict__ x, const u16* __restrict__ qw1b,
                                                const float* __restrict__ absum, u16* __restrict__ p1raw,
                                                float* __restrict__ gs, float* __restrict__ gq){
  __shared__ float xs[3*34*36];              // fp32 halo image, data y=1..32, x=2..33
  __shared__ __align__(16) u16 acol[256*40]; // im2col chunk: 256 rows x 40 u16 (32 used)
  __shared__ float ls1[64], ls2[64];
  int n = blockIdx.x, t = threadIdx.x;
  if (t < 64){ ls1[t] = 0.f; ls2[t] = 0.f; }
  for (int i = t; i < 3672; i += 256) xs[i] = 0.f;
  __syncthreads();
  const float4* xg = (const float4*)(x + (size_t)n * 3072);
  for (int i = t; i < 768; i += 256){
    float4 v = xg[i];
    int ci = i >> 8, rem = i & 255, y = rem >> 3, xq = (rem & 7) * 4;
    int base = ci*1224 + (y+1)*36 + 2 + xq;
    xs[base+0] = v.x; xs[base+1] = v.y; xs[base+2] = v.z; xs[base+3] = v.w;
  }
  int w = t >> 6, lane = t & 63, l15 = lane & 15, q = lane >> 4;
  // B-frags: 4 co-tiles, sign weights (+-1 exact in bf16)
  const s8v* bp = (const s8v*)qw1b;
  s8v bf[4];
  #pragma unroll
  for (int nt = 0; nt < 4; ++nt) bf[nt] = bp[nt*64 + lane];
  float alpha = absum[0] * (1.f/1728.f);
  u16* p1img = p1raw + (size_t)n * 16384;
  float s1v[4], s2v[4];
  #pragma unroll
  for (int nt = 0; nt < 4; ++nt){ s1v[nt] = 0.f; s2v[nt] = 0.f; }
  for (int chunk = 0; chunk < 4; ++chunk){
    __syncthreads();   // also covers xs staging on first iter; protects acol reuse after
    // build: this thread builds im2col row (local) t for global m = chunk*256 + t
    {
      int mg = chunk*256 + t;
      int g = mg >> 2, s = mg & 3;
      int iy = 2*(g >> 4) + (s >> 1), ix = 2*(g & 15) + (s & 1);
      const float* xb = xs + iy*36 + ix + 1;   // + ci*1224 + dy*36 + dx (imm)
      u32 pk2[16];
      #pragma unroll
      for (int kk = 0; kk < 16; ++kk){
        int k0 = 2*kk, k1 = 2*kk + 1;
        u32 lo = (k0 < 27) ? (u32)f2bf(xb[(k0/9)*1224 + ((k0%9)/3)*36 + (k0%3)]) : 0u;
        u32 hi = (k1 < 27) ? (u32)f2bf(xb[(k1/9)*1224 + ((k1%9)/3)*36 + (k1%3)]) : 0u;
        pk2[kk] = lo | (hi << 16);
      }
      u32* ar = (u32*)(acol + t*40);
      #pragma unroll
      for (int v = 0; v < 4; ++v)
        *(uint4*)(ar + v*4) = make_uint4(pk2[v*4], pk2[v*4+1], pk2[v*4+2], pk2[v*4+3]);
    }
    __syncthreads();
    // MFMA: wave w handles local tiles w*4..w*4+3 (16 rows each)
    #pragma unroll
    for (int i = 0; i < 4; ++i){
      int tl = w*4 + i;
      s8v av = *(const s8v*)(acol + (tl*16 + l15)*40 + q*8);
      int g = chunk*64 + tl*4 + q;       // pooled pixel this lane owns
      u16* drow = p1img + g*64 + l15;
      #pragma unroll
      for (int nt = 0; nt < 4; ++nt){
        f4v c = (f4v)(0.0f);
        c = __builtin_amdgcn_mfma_f32_16x16x32_bf16(av, bf[nt], c, 0, 0, 0);
        s1v[nt] += c[0] + c[1] + c[2] + c[3];
        s2v[nt] += c[0]*c[0] + c[1]*c[1] + c[2]*c[2] + c[3]*c[3];
        float pm = fmaxf(fmaxf(c[0], c[1]), fmaxf(c[2], c[3]));
        drow[nt*16] = f2bf(pm * alpha);
      }
    }
  }
  // stats: reduce over q-groups (lanes sharing l15), then LDS, then global
  #pragma unroll
  for (int nt = 0; nt < 4; ++nt){
    s1v[nt] += __shfl_xor(s1v[nt], 16); s1v[nt] += __shfl_xor(s1v[nt], 32);
    s2v[nt] += __shfl_xor(s2v[nt], 16); s2v[nt] += __shfl_xor(s2v[nt], 32);
  }
  if (q == 0){
    #pragma unroll
    for (int nt = 0; nt < 4; ++nt){
      atomicAdd(&ls1[nt*16 + l15], s1v[nt]);
      atomicAdd(&ls2[nt*16 + l15], s2v[nt]);
    }
  }
  __syncthreads();
  if (t < 64){
    atomicAdd(gs + t, ls1[t] * alpha);
    atomicAdd(gq + t, ls2[t] * alpha * alpha);
  }
}

// ---------- finalize BN affine params ----------
__global__ void k_fin(const float* __restrict__ sum, const float* __restrict__ sumsq,
                      const float* __restrict__ g, const float* __restrict__ b,
                      float* __restrict__ scale, float* __restrict__ bias, int C, float invc){
  int c = blockIdx.x * blockDim.x + threadIdx.x;
  if (c >= C) return;
  float m = sum[c] * invc;
  float var = sumsq[c] * invc - m*m;
  float sc = g[c] * rsqrtf(var + 1e-5f);
  scale[c] = sc;
  bias[c] = b[c] - m * sc;
}

// ---------- conv2 via MFMA, barrier-free K-loop; BN1+ReLU fused into staging ----------
__global__ __launch_bounds__(256, 2) void k_conv2m(const u16* __restrict__ p1raw, const u16* __restrict__ qw2b,
                                                   const float* __restrict__ absum,
                                                   const float* __restrict__ sc1, const float* __restrict__ bi1,
                                                   u16* __restrict__ h2t,
                                                   float* __restrict__ gs, float* __restrict__ gq){
  __shared__ __align__(16) u16 img[16384];   // 32 KB, XOR-swizzled 16B units
  __shared__ float ls1[128], ls2[128];
  int n = blockIdx.x, t = threadIdx.x;
  if (t < 128){ ls1[t] = 0.f; ls2[t] = 0.f; }
  int c0 = (t & 7) * 8;
  float scv[8], biv[8];
  *(float4*)(scv)     = *(const float4*)(sc1 + c0);
  *(float4*)(scv + 4) = *(const float4*)(sc1 + c0 + 4);
  *(float4*)(biv)     = *(const float4*)(bi1 + c0);
  *(float4*)(biv + 4) = *(const float4*)(bi1 + c0 + 4);
  const u16* src = p1raw + (size_t)n * 16384;
  #pragma unroll
  for (int i = 0; i < 8; ++i){
    int id = i*256 + t;            // = px*8 + unit, unit == t&7
    int px = id >> 3, unit = id & 7;
    int su = unit ^ (px & 7);
    u16x8 v = *(const u16x8*)(src + id*8);
    u16x8 o;
    #pragma unroll
    for (int j = 0; j < 8; ++j)
      o[j] = f2bf(fmaxf(bf2f(v[j]) * scv[j] + biv[j], 0.f));
    *(u16x8*)(img + px*64 + su*8) = o;
  }
  __syncthreads();
  int w = t >> 6, lane = t & 63, l15 = lane & 15, q = lane >> 4;
  const s8v* bp = (const s8v*)qw2b;
  f4v acc[4][8];
  #pragma unroll
  for (int a = 0; a < 4; ++a)
    #pragma unroll
    for (int b = 0; b < 8; ++b) acc[a][b] = (f4v)(0.0f);
  for (int dy = 0; dy < 3; ++dy){
    for (int dx = 0; dx < 3; ++dx){
      int s = dy*3 + dx;
      int xv = l15 + dx - 1;
      bool vx = (xv >= 0) && (xv < 16);
      int xc = min(max(xv, 0), 15);
      #pragma unroll
      for (int ks = 0; ks < 2; ++ks){
        s8v bf[8];
        #pragma unroll
        for (int nt = 0; nt < 8; ++nt) bf[nt] = bp[((s*2 + ks)*8 + nt)*64 + lane];
        #pragma unroll
        for (int mt = 0; mt < 4; ++mt){
          int yv = w*4 + mt + dy - 1;
          if (yv < 0 || yv > 15) continue;
          int px = yv*16 + xc;
          int su = (ks*4 + q) ^ (px & 7);
          s8v av = *(const s8v*)(img + px*64 + su*8);
          if (!vx) av = (s8v)(short)0;
          #pragma unroll
          for (int nt = 0; nt < 8; ++nt)
            acc[mt][nt] = __builtin_amdgcn_mfma_f32_16x16x32_bf16(av, bf[nt], acc[mt][nt], 0, 0, 0);
        }
      }
    }
  }
  float alpha = absum[1] * (1.f/73728.f);
  float s1v[8], s2v[8];
  #pragma unroll
  for (int nt = 0; nt < 8; ++nt){ s1v[nt] = 0.f; s2v[nt] = 0.f; }
  #pragma unroll
  for (int mt = 0; mt < 4; ++mt){
    int y = w*4 + mt;
    #pragma unroll
    for (int r = 0; r < 4; ++r){
      int px = y*16 + q*4 + r;
      u16x8 pk;
      #pragma unroll
      for (int nt = 0; nt < 8; ++nt){
        float v = acc[mt][nt][r] * alpha;
        s1v[nt] += v; s2v[nt] += v*v;
        pk[nt] = f2bf(v);
      }
      *(u16x8*)(h2t + ((size_t)n*256 + px)*128 + l15*8) = pk;
    }
  }
  #pragma unroll
  for (int nt = 0; nt < 8; ++nt){
    s1v[nt] += __shfl_xor(s1v[nt], 16); s1v[nt] += __shfl_xor(s1v[nt], 32);
    s2v[nt] += __shfl_xor(s2v[nt], 16); s2v[nt] += __shfl_xor(s2v[nt], 32);
  }
  if (q == 0){
    #pragma unroll
    for (int nt = 0; nt < 8; ++nt){
      atomicAdd(&ls1[l15*8 + nt], s1v[nt]);
      atomicAdd(&ls2[l15*8 + nt], s2v[nt]);
    }
  }
  __syncthreads();
  if (t < 128){ atomicAdd(gs + t, ls1[t]); atomicAdd(gq + t, ls2[t]); }
}

// ---------- BN2+ReLU+pool channel-last: h2t[1024][16x16][128] -> p2[1024][8x8][128] ----------
__global__ __launch_bounds__(256) void k_pool2t(const u16* __restrict__ h2t, u16* __restrict__ p2,
                                                const float* __restrict__ sc, const float* __restrict__ bi){
  __shared__ float lsc[128], lbi[128];
  int n = blockIdx.x, t = threadIdx.x;
  if (t < 128) lsc[t] = sc[t];
  else lbi[t - 128] = bi[t - 128];
  __syncthreads();
  int opx = t >> 2, cq = t & 3;
  int oy = opx >> 3, ox = opx & 7;
  const u16* base = h2t + (size_t)n*32768 + ((oy*2)*16 + ox*2)*128 + cq*32;
  u16* dst = p2 + (size_t)n*8192 + opx*128 + cq*32;
  #pragma unroll
  for (int v = 0; v < 4; ++v){
    u16x8 a0 = *(const u16x8*)(base + v*8);
    u16x8 a1 = *(const u16x8*)(base + 128 + v*8);
    u16x8 a2 = *(const u16x8*)(base + 2048 + v*8);
    u16x8 a3 = *(const u16x8*)(base + 2176 + v*8);
    u16x8 o;
    #pragma unroll
    for (int j = 0; j < 8; ++j){
      int c = cq*32 + v*8 + j;
      float m = fmaxf(fmaxf(bf2f(a0[j]), bf2f(a1[j])), fmaxf(bf2f(a2[j]), bf2f(a3[j])));
      o[j] = f2bf(fmaxf(m * lsc[c] + lbi[c], 0.f));
    }
    *(u16x8*)(dst + v*8) = o;
  }
}

// ---------- fc1 via MFMA, k-split 16: p2[1024][8192] x signs -> h3p[16][1024][256] ----------
__global__ __launch_bounds__(256) void k_fc1m(const u16* __restrict__ p2, const u16* __restrict__ qfc1b,
                                              const float* __restrict__ absum, float* __restrict__ h3p){
  int t = threadIdx.x;
  int bm = blockIdx.x, bn = blockIdx.y, kb = blockIdx.z;
  int w = t >> 6, lane = t & 63, l15 = lane & 15, q = lane >> 4;
  int rowbase = bm*128 + (w >> 1)*64;
  int ntb = bn*8 + (w & 1)*4;
  const s8v* bp = (const s8v*)qfc1b;
  f4v acc[4][4];
  #pragma unroll
  for (int a = 0; a < 4; ++a)
    #pragma unroll
    for (int b = 0; b < 4; ++b) acc[a][b] = (f4v)(0.0f);
  #pragma unroll 2
  for (int ks = 0; ks < 16; ++ks){
    int kst = kb*16 + ks;
    s8v bf[4], af[4];
    #pragma unroll
    for (int nt = 0; nt < 4; ++nt) bf[nt] = bp[(kst*16 + ntb + nt)*64 + lane];
    #pragma unroll
    for (int mt = 0; mt < 4; ++mt)
      af[mt] = *(const s8v*)(p2 + (size_t)(rowbase + mt*16 + l15)*8192 + kst*32 + q*8);
    #pragma unroll
    for (int mt = 0; mt < 4; ++mt)
      #pragma unroll
      for (int nt = 0; nt < 4; ++nt)
        acc[mt][nt] = __builtin_amdgcn_mfma_f32_16x16x32_bf16(af[mt], bf[nt], acc[mt][nt], 0, 0, 0);
  }
  float alpha = absum[2] * (1.f/2097152.f);
  float* dst = h3p + (size_t)kb * 262144;
  #pragma unroll
  for (int mt = 0; mt < 4; ++mt)
    #pragma unroll
    for (int nt = 0; nt < 4; ++nt){
      int col = (ntb + nt)*16 + l15;
      #pragma unroll
      for (int r = 0; r < 4; ++r)
        dst[(size_t)(rowbase + mt*16 + q*4 + r)*256 + col] = acc[mt][nt][r] * alpha;
    }
}

// ---------- reduce k-split slabs + BN3 stats + materialize h3 ----------
__global__ __launch_bounds__(256) void k_fin3f(const float* __restrict__ h3p, float* __restrict__ h3,
                                               float* __restrict__ s3, float* __restrict__ q3){
  int jb = blockIdx.x, ns = blockIdx.y, t = threadIdx.x;
  int jj = t & 31, nn = t >> 5;
  int j = jb*32 + jj;
  float s1 = 0.f, s2 = 0.f;
  for (int i = nn; i < 128; i += 8){
    int n = i*8 + ns;
    float v = 0.f;
    #pragma unroll 8
    for (int kb = 0; kb < 16; ++kb) v += h3p[(size_t)kb*262144 + n*256 + j];
    h3[n*256 + j] = v;
    s1 += v; s2 += v*v;
  }
  __shared__ float l1[256], l2[256];
  l1[t] = s1; l2[t] = s2;
  __syncthreads();
  if (t < 32){
    float a = 0.f, b = 0.f;
    #pragma unroll
    for (int k = 0; k < 8; ++k){ a += l1[t+32*k]; b += l2[t+32*k]; }
    atomicAdd(s3 + jb*32 + t, a); atomicAdd(q3 + jb*32 + t, b);
  }
}

// ---------- fc2: relu(bn3(h3)) @ sign(wfc2)^T -> out[1024,10] fp32 ----------
__global__ __launch_bounds__(64) void k_fc2(const float* __restrict__ h3, const float* __restrict__ qwfc2,
                                            const float* __restrict__ absum, const float* __restrict__ scale,
                                            const float* __restrict__ bias, float* __restrict__ out){
  int n = blockIdx.x, lane = threadIdx.x;
  float a[4];
  #pragma unroll
  for (int i = 0; i < 4; ++i){
    int j = lane + 64*i;
    float v = h3[(size_t)n*256 + j] * scale[j] + bias[j];
    a[i] = fmaxf(v, 0.f);
  }
  float alpha = absum[3] * (1.f/2560.f);
  #pragma unroll
  for (int k = 0; k < 10; ++k){
    float p = 0.f;
    #pragma unroll
    for (int i = 0; i < 4; ++i) p += a[i] * qwfc2[k*256 + lane + 64*i];
    #pragma unroll
    for (int off = 32; off > 0; off >>= 1) p += __shfl_down(p, off);
    if (lane == 0) out[n*10 + k] = p * alpha;
  }
}

extern "C" void kernel_launch(void* const* d_in, const int* in_sizes, int n_in,
                              void* d_out, int out_size, void* d_ws, size_t ws_size,
                              hipStream_t stream){
  (void)in_sizes; (void)n_in; (void)out_size; (void)ws_size;
  const float* x    = (const float*)d_in[0];
  const float* w1   = (const float*)d_in[1];
  const float* g1   = (const float*)d_in[2];
  const float* b1   = (const float*)d_in[3];
  const float* w2   = (const float*)d_in[4];
  const float* g2   = (const float*)d_in[5];
  const float* b2   = (const float*)d_in[6];
  const float* wfc1 = (const float*)d_in[7];
  const float* g3   = (const float*)d_in[8];
  const float* b3   = (const float*)d_in[9];
  const float* wfc2 = (const float*)d_in[10];
  float* out = (float*)d_out;

  float* wsf = (float*)d_ws;
  char*  wsb = (char*)d_ws;
  float* absum = wsf;
  float* s1 = wsf + 16;   float* q1 = wsf + 80;
  float* s2 = wsf + 144;  float* q2 = wsf + 272;
  float* s3 = wsf + 1024; float* q3 = wsf + 1280;
  float* sc1 = wsf + 1536; float* bi1 = wsf + 1600;
  float* sc2 = wsf + 1664; float* bi2 = wsf + 1792;
  float* sc3 = wsf + 2048; float* bi3 = wsf + 2304;
  u16*   qw1b  = (u16*)(wsf + 4096);                 // 2048 u16 conv1 B-frags
  u16*   qw2b  = (u16*)(wsb + (64u << 10));          // 144 KB bf16 B-frags
  float* qwfc2 = (float*)(wsb + (256u << 10));       // 10 KB fp32
  float* h3    = (float*)(wsb + (1ull << 20));       // 1 MB fp32 [1024][256]
  u16*   qfc1b = (u16*)(wsb + (2ull << 20));         // 4 MB bf16 B-frags
  u16*   p1t   = (u16*)(wsb + (8ull << 20) + 4096);  // 32 MB bf16 [1024][256][64]
  u16*   h2t   = (u16*)(wsb + (48ull << 20));        // 64 MB bf16 [1024][256][128]
  u16*   p2    = (u16*)(wsb + (112ull << 20));       // 16 MB bf16 [1024][8192] (channel-last k)
  float* h3p   = (float*)(wsb + (128ull << 20));     // 16 MB fp32 [16][1024][256]

  k_zero<<<10, 256, 0, stream>>>(wsf, 2560);
  k_absum<<<98, 256, 0, stream>>>(w1, w2, wfc1, wfc2, absum);
  k_signgen<<<8498, 256, 0, stream>>>(w1, w2, wfc1, wfc2, qw1b, qw2b, qfc1b, qwfc2);
  k_conv1m<<<1024, 256, 0, stream>>>(x, qw1b, absum, p1t, s1, q1);
  k_fin<<<1, 64, 0, stream>>>(s1, q1, g1, b1, sc1, bi1, 64, 1.f/1048576.f);
  k_conv2m<<<1024, 256, 0, stream>>>(p1t, qw2b, absum, sc1, bi1, h2t, s2, q2);
  k_fin<<<1, 128, 0, stream>>>(s2, q2, g2, b2, sc2, bi2, 128, 1.f/262144.f);
  k_pool2t<<<1024, 256, 0, stream>>>(h2t, p2, sc2, bi2);
  k_fc1m<<<dim3(8, 2, 16), 256, 0, stream>>>(p2, qfc1b, absum, h3p);
  k_fin3f<<<dim3(8, 8), 256, 0, stream>>>(h3p, h3, s3, q3);
  k_fin<<<1, 256, 0, stream>>>(s3, q3, g3, b3, sc3, bi3, 256, 1.f/1024.f);
  k_fc2<<<1024, 64, 0, stream>>>(h3, qwfc2, absum, sc3, bi3, out);
}

// Round 10
// 263.811 us; speedup vs baseline: 3.7313x; 1.1242x over previous
//
#include <hip/hip_runtime.h>
#include <stdint.h>

typedef unsigned short u16;
typedef unsigned int u32;
typedef __attribute__((ext_vector_type(8))) short s8v;   // 8 bf16 = 4 VGPR (MFMA A/B frag)
typedef __attribute__((ext_vector_type(4))) float f4v;   // MFMA C/D frag
typedef __attribute__((ext_vector_type(8))) u16 u16x8;

// ---------- bf16 helpers ----------
__device__ __forceinline__ float bf2f(u16 u){
  union { u32 i; float f; } v; v.i = ((u32)u) << 16; return v.f;
}
__device__ __forceinline__ u16 f2bf(float f){
  union { float f; u32 i; } v; v.f = f;
  u32 i = v.i;
  return (u16)((i + 0x7fffu + ((i >> 16) & 1u)) >> 16); // RNE
}
__device__ __forceinline__ float sgnf(float w){
  return (w > 0.f) ? 1.f : ((w < 0.f) ? -1.f : 0.f);
}
__device__ __forceinline__ u16 sgn_bf(float w){
  return (w > 0.f) ? (u16)0x3F80 : ((w < 0.f) ? (u16)0xBF80 : (u16)0);
}

// ---------- block reduction (256 threads = 4 waves) ----------
__device__ __forceinline__ void block_reduce2(float& a, float& b){
  #pragma unroll
  for (int off = 32; off > 0; off >>= 1){
    a += __shfl_down(a, off);
    b += __shfl_down(b, off);
  }
  __shared__ float ra[4], rb[4];
  int lane = threadIdx.x & 63, w = threadIdx.x >> 6;
  __syncthreads();
  if (lane == 0){ ra[w] = a; rb[w] = b; }
  __syncthreads();
  if (threadIdx.x == 0){
    a = ra[0] + ra[1] + ra[2] + ra[3];
    b = rb[0] + rb[1] + rb[2] + rb[3];
  }
}

// ---------- sum(|w|) for the 4 weight tensors ----------
__global__ __launch_bounds__(256) void k_absum(const float* __restrict__ w1, const float* __restrict__ w2,
                                               const float* __restrict__ wfc1, const float* __restrict__ wfc2,
                                               float* __restrict__ absum){
  int b = blockIdx.x, t = threadIdx.x;
  const float* src; int n0, cnt, slot;
  if (b < 64)      { src = wfc1; slot = 2; cnt = 2097152/64; n0 = b * cnt; }
  else if (b < 96) { src = w2;   slot = 1; cnt = 73728/32;   n0 = (b-64) * cnt; }
  else if (b == 96){ src = w1;   slot = 0; cnt = 1728;       n0 = 0; }
  else             { src = wfc2; slot = 3; cnt = 2560;       n0 = 0; }
  float s = 0.f, d = 0.f;
  for (int i = t; i < cnt; i += 256) s += fabsf(src[n0 + i]);
  block_reduce2(s, d);
  if (t == 0) atomicAdd(absum + slot, s);
}

// ---------- generate all quantized weight forms ----------
__global__ __launch_bounds__(256) void k_signgen(const float* __restrict__ w1, const float* __restrict__ w2,
                                                 const float* __restrict__ wfc1, const float* __restrict__ wfc2,
                                                 u16* __restrict__ qw1b, u16* __restrict__ qw2b,
                                                 u16* __restrict__ qfc1b, float* __restrict__ qwfc2){
  int i = blockIdx.x * 256 + threadIdx.x;
  if (i < 2097152){
    int j = i & 7, lane = (i >> 3) & 63, fid = i >> 9;
    int kstep = fid >> 4, nt = fid & 15;
    int co = nt*16 + (lane & 15);
    int k_phys = kstep*32 + (lane >> 4)*8 + j;
    int px = k_phys >> 7, c = k_phys & 127;
    qfc1b[i] = sgn_bf(wfc1[(size_t)co*8192 + c*64 + px]);
  } else if (i < 2097152 + 73728){
    int i2 = i - 2097152;
    int j = i2 & 7, lane = (i2 >> 3) & 63, fid = i2 >> 9;  // 0..143
    int s = fid >> 4, ks = (fid >> 3) & 1, nt = fid & 7;
    int co = (lane & 15)*8 + nt;
    int c = ks*32 + (lane >> 4)*8 + j;
    qw2b[i2] = sgn_bf(w2[((size_t)co*64 + c)*9 + s]);
  } else if (i < 2097152 + 73728 + 2048){
    int i3 = i - (2097152 + 73728);
    int j = i3 & 7, lane = (i3 >> 3) & 63, nt = i3 >> 9;   // 0..3
    int co = nt*16 + (lane & 15);
    int k = (lane >> 4)*8 + j;
    qw1b[i3] = (k < 27) ? sgn_bf(w1[co*27 + k]) : (u16)0;
  } else if (i < 2097152 + 73728 + 2048 + 2560){
    int i4 = i - (2097152 + 73728 + 2048);
    qwfc2[i4] = sgnf(wfc2[i4]);
  }
}

// ---------- conv1 via MFMA: im2col in LDS + fused BN1 stats + in-lane 2x2 pool ----------
__global__ __launch_bounds__(256) void k_conv1m(const float* __restrict__ x, const u16* __restrict__ qw1b,
                                                const float* __restrict__ absum, u16* __restrict__ p1raw,
                                                float* __restrict__ gs, float* __restrict__ gq){
  __shared__ float xs[3*34*36];              // fp32 halo image, data y=1..32, x=2..33
  __shared__ __align__(16) u16 acol[256*40]; // im2col chunk: 256 rows x 40 u16 (32 used)
  __shared__ float ls1[64], ls2[64];
  int n = blockIdx.x, t = threadIdx.x;
  if (t < 64){ ls1[t] = 0.f; ls2[t] = 0.f; }
  for (int i = t; i < 3672; i += 256) xs[i] = 0.f;
  __syncthreads();
  const float4* xg = (const float4*)(x + (size_t)n * 3072);
  for (int i = t; i < 768; i += 256){
    float4 v = xg[i];
    int ci = i >> 8, rem = i & 255, y = rem >> 3, xq = (rem & 7) * 4;
    int base = ci*1224 + (y+1)*36 + 2 + xq;
    xs[base+0] = v.x; xs[base+1] = v.y; xs[base+2] = v.z; xs[base+3] = v.w;
  }
  int w = t >> 6, lane = t & 63, l15 = lane & 15, q = lane >> 4;
  const s8v* bp = (const s8v*)qw1b;
  s8v bf[4];
  #pragma unroll
  for (int nt = 0; nt < 4; ++nt) bf[nt] = bp[nt*64 + lane];
  float alpha = absum[0] * (1.f/1728.f);
  u16* p1img = p1raw + (size_t)n * 16384;
  float s1v[4], s2v[4];
  #pragma unroll
  for (int nt = 0; nt < 4; ++nt){ s1v[nt] = 0.f; s2v[nt] = 0.f; }
  for (int chunk = 0; chunk < 4; ++chunk){
    __syncthreads();
    {
      int mg = chunk*256 + t;
      int g = mg >> 2, s = mg & 3;
      int iy = 2*(g >> 4) + (s >> 1), ix = 2*(g & 15) + (s & 1);
      const float* xb = xs + iy*36 + ix + 1;
      u32 pk2[16];
      #pragma unroll
      for (int kk = 0; kk < 16; ++kk){
        int k0 = 2*kk, k1 = 2*kk + 1;
        u32 lo = (k0 < 27) ? (u32)f2bf(xb[(k0/9)*1224 + ((k0%9)/3)*36 + (k0%3)]) : 0u;
        u32 hi = (k1 < 27) ? (u32)f2bf(xb[(k1/9)*1224 + ((k1%9)/3)*36 + (k1%3)]) : 0u;
        pk2[kk] = lo | (hi << 16);
      }
      u32* ar = (u32*)(acol + t*40);
      #pragma unroll
      for (int v = 0; v < 4; ++v)
        *(uint4*)(ar + v*4) = make_uint4(pk2[v*4], pk2[v*4+1], pk2[v*4+2], pk2[v*4+3]);
    }
    __syncthreads();
    #pragma unroll
    for (int i = 0; i < 4; ++i){
      int tl = w*4 + i;
      s8v av = *(const s8v*)(acol + (tl*16 + l15)*40 + q*8);
      int g = chunk*64 + tl*4 + q;
      u16* drow = p1img + g*64 + l15;
      #pragma unroll
      for (int nt = 0; nt < 4; ++nt){
        f4v c = (f4v)(0.0f);
        c = __builtin_amdgcn_mfma_f32_16x16x32_bf16(av, bf[nt], c, 0, 0, 0);
        s1v[nt] += c[0] + c[1] + c[2] + c[3];
        s2v[nt] += c[0]*c[0] + c[1]*c[1] + c[2]*c[2] + c[3]*c[3];
        float pm = fmaxf(fmaxf(c[0], c[1]), fmaxf(c[2], c[3]));
        drow[nt*16] = f2bf(pm * alpha);
      }
    }
  }
  #pragma unroll
  for (int nt = 0; nt < 4; ++nt){
    s1v[nt] += __shfl_xor(s1v[nt], 16); s1v[nt] += __shfl_xor(s1v[nt], 32);
    s2v[nt] += __shfl_xor(s2v[nt], 16); s2v[nt] += __shfl_xor(s2v[nt], 32);
  }
  if (q == 0){
    #pragma unroll
    for (int nt = 0; nt < 4; ++nt){
      atomicAdd(&ls1[nt*16 + l15], s1v[nt]);
      atomicAdd(&ls2[nt*16 + l15], s2v[nt]);
    }
  }
  __syncthreads();
  if (t < 64){
    atomicAdd(gs + t, ls1[t] * alpha);
    atomicAdd(gq + t, ls2[t] * alpha * alpha);
  }
}

// ---------- conv2 via MFMA, barrier-free K-loop; BN1 inline; in-register 2x2 pool ----------
// p1raw[1024][256px][64c] -> p2raw[1024][64 pooled px][128co] bf16 (= max4(conv2)*alpha2).
// BN1 affine+ReLU fused into staging; BN1 scale/bias computed inline from raw sums.
// BN2 stats (pre-pool, fp32, exact) fused; stats LDS overlays img (LDS = exactly 32 KB -> 5 blocks/CU).
__global__ __launch_bounds__(256, 2) void k_conv2m(const u16* __restrict__ p1raw, const u16* __restrict__ qw2b,
                                                   const float* __restrict__ absum,
                                                   const float* __restrict__ s1, const float* __restrict__ q1,
                                                   const float* __restrict__ g1, const float* __restrict__ b1,
                                                   u16* __restrict__ p2raw,
                                                   float* __restrict__ gs, float* __restrict__ gq){
  __shared__ __align__(16) u16 img[16384];   // 32 KB exactly; reused for stats after compute
  int n = blockIdx.x, t = threadIdx.x;
  // BN1 params for this thread's staged channels c0..c0+7 (computed inline, no k_fin)
  int c0 = (t & 7) * 8;
  float scv[8], biv[8];
  #pragma unroll
  for (int j = 0; j < 8; ++j){
    float m = s1[c0+j] * (1.f/1048576.f);
    float var = q1[c0+j] * (1.f/1048576.f) - m*m;
    float sc = g1[c0+j] * rsqrtf(var + 1e-5f);
    scv[j] = sc; biv[j] = b1[c0+j] - m*sc;
  }
  const u16* src = p1raw + (size_t)n * 16384;
  #pragma unroll
  for (int i = 0; i < 8; ++i){
    int id = i*256 + t;            // = px*8 + unit, unit == t&7
    int px = id >> 3, unit = id & 7;
    int su = unit ^ (px & 7);
    u16x8 v = *(const u16x8*)(src + id*8);
    u16x8 o;
    #pragma unroll
    for (int j = 0; j < 8; ++j)
      o[j] = f2bf(fmaxf(bf2f(v[j]) * scv[j] + biv[j], 0.f));
    *(u16x8*)(img + px*64 + su*8) = o;
  }
  __syncthreads();
  int w = t >> 6, lane = t & 63, l15 = lane & 15, q = lane >> 4;
  const s8v* bp = (const s8v*)qw2b;
  f4v acc[4][8];
  #pragma unroll
  for (int a = 0; a < 4; ++a)
    #pragma unroll
    for (int b = 0; b < 8; ++b) acc[a][b] = (f4v)(0.0f);
  #pragma unroll
  for (int dy = 0; dy < 3; ++dy){
    #pragma unroll
    for (int dx = 0; dx < 3; ++dx){
      int s = dy*3 + dx;
      int xv = l15 + dx - 1;
      bool vx = (xv >= 0) && (xv < 16);
      int xc = min(max(xv, 0), 15);
      #pragma unroll
      for (int ks = 0; ks < 2; ++ks){
        s8v bf[8];
        #pragma unroll
        for (int nt = 0; nt < 8; ++nt) bf[nt] = bp[((s*2 + ks)*8 + nt)*64 + lane];
        #pragma unroll
        for (int mt = 0; mt < 4; ++mt){
          int yv = w*4 + mt + dy - 1;
          if (yv < 0 || yv > 15) continue;
          int px = yv*16 + xc;
          int su = (ks*4 + q) ^ (px & 7);
          s8v av = *(const s8v*)(img + px*64 + su*8);
          if (!vx) av = (s8v)(short)0;
          #pragma unroll
          for (int nt = 0; nt < 8; ++nt)
            acc[mt][nt] = __builtin_amdgcn_mfma_f32_16x16x32_bf16(av, bf[nt], acc[mt][nt], 0, 0, 0);
        }
      }
    }
  }
  float alpha = absum[1] * (1.f/73728.f);
  float s1v[8], s2v[8];
  #pragma unroll
  for (int nt = 0; nt < 8; ++nt){ s1v[nt] = 0.f; s2v[nt] = 0.f; }
  // stats over all 16 (mt,r) values per nt + in-register 2x2 pool -> 4 pooled px per lane
  #pragma unroll
  for (int mp = 0; mp < 2; ++mp){           // pooled row pair (rows 2mp, 2mp+1 of this wave)
    #pragma unroll
    for (int rp = 0; rp < 2; ++rp){         // pooled col pair (cols 2rp, 2rp+1 of this lane)
      u16x8 pk;
      #pragma unroll
      for (int nt = 0; nt < 8; ++nt){
        float v0 = acc[2*mp][nt][2*rp]     * alpha;
        float v1 = acc[2*mp][nt][2*rp+1]   * alpha;
        float v2 = acc[2*mp+1][nt][2*rp]   * alpha;
        float v3 = acc[2*mp+1][nt][2*rp+1] * alpha;
        s1v[nt] += v0 + v1 + v2 + v3;
        s2v[nt] += v0*v0 + v1*v1 + v2*v2 + v3*v3;
        pk[nt] = f2bf(fmaxf(fmaxf(v0, v1), fmaxf(v2, v3)));
      }
      int opx = (w*2 + mp)*8 + (q*2 + rp);  // pooled 8x8 index
      *(u16x8*)(p2raw + ((size_t)n*64 + opx)*128 + l15*8) = pk;
    }
  }
  #pragma unroll
  for (int nt = 0; nt < 8; ++nt){
    s1v[nt] += __shfl_xor(s1v[nt], 16); s1v[nt] += __shfl_xor(s1v[nt], 32);
    s2v[nt] += __shfl_xor(s2v[nt], 16); s2v[nt] += __shfl_xor(s2v[nt], 32);
  }
  __syncthreads();                 // all waves done reading img -> reuse as stats LDS
  float* ls = (float*)img;         // ls[0..127]=sum, ls[128..255]=sumsq
  if (t < 256) ls[t] = 0.f;
  __syncthreads();
  if (q == 0){
    #pragma unroll
    for (int nt = 0; nt < 8; ++nt){
      atomicAdd(&ls[l15*8 + nt], s1v[nt]);
      atomicAdd(&ls[128 + l15*8 + nt], s2v[nt]);
    }
  }
  __syncthreads();
  if (t < 128){ atomicAdd(gs + t, ls[t]); atomicAdd(gq + t, ls[128 + t]); }
}

// ---------- BN2 affine + ReLU in-place on p2[1024][64px][128c] (params inline) ----------
__global__ __launch_bounds__(256) void k_bn2(u16* __restrict__ p2,
                                             const float* __restrict__ s2, const float* __restrict__ q2,
                                             const float* __restrict__ g2, const float* __restrict__ b2){
  size_t i = (size_t)blockIdx.x * 256 + threadIdx.x;   // unit of 8 u16
  int c0 = ((int)(i & 15)) * 8;
  float scv[8], biv[8];
  #pragma unroll
  for (int j = 0; j < 8; ++j){
    float m = s2[c0+j] * (1.f/262144.f);
    float var = q2[c0+j] * (1.f/262144.f) - m*m;
    float sc = g2[c0+j] * rsqrtf(var + 1e-5f);
    scv[j] = sc; biv[j] = b2[c0+j] - m*sc;
  }
  u16x8 v = *(u16x8*)(p2 + i*8);
  u16x8 o;
  #pragma unroll
  for (int j = 0; j < 8; ++j)
    o[j] = f2bf(fmaxf(bf2f(v[j]) * scv[j] + biv[j], 0.f));
  *(u16x8*)(p2 + i*8) = o;
}

// ---------- fc1 via MFMA, k-split 16: p2[1024][8192] x signs -> h3p[16][1024][256] ----------
__global__ __launch_bounds__(256) void k_fc1m(const u16* __restrict__ p2, const u16* __restrict__ qfc1b,
                                              const float* __restrict__ absum, float* __restrict__ h3p){
  int t = threadIdx.x;
  int bm = blockIdx.x, bn = blockIdx.y, kb = blockIdx.z;
  int w = t >> 6, lane = t & 63, l15 = lane & 15, q = lane >> 4;
  int rowbase = bm*128 + (w >> 1)*64;
  int ntb = bn*8 + (w & 1)*4;
  const s8v* bp = (const s8v*)qfc1b;
  f4v acc[4][4];
  #pragma unroll
  for (int a = 0; a < 4; ++a)
    #pragma unroll
    for (int b = 0; b < 4; ++b) acc[a][b] = (f4v)(0.0f);
  #pragma unroll 2
  for (int ks = 0; ks < 16; ++ks){
    int kst = kb*16 + ks;
    s8v bf[4], af[4];
    #pragma unroll
    for (int nt = 0; nt < 4; ++nt) bf[nt] = bp[(kst*16 + ntb + nt)*64 + lane];
    #pragma unroll
    for (int mt = 0; mt < 4; ++mt)
      af[mt] = *(const s8v*)(p2 + (size_t)(rowbase + mt*16 + l15)*8192 + kst*32 + q*8);
    #pragma unroll
    for (int mt = 0; mt < 4; ++mt)
      #pragma unroll
      for (int nt = 0; nt < 4; ++nt)
        acc[mt][nt] = __builtin_amdgcn_mfma_f32_16x16x32_bf16(af[mt], bf[nt], acc[mt][nt], 0, 0, 0);
  }
  float alpha = absum[2] * (1.f/2097152.f);
  float* dst = h3p + (size_t)kb * 262144;
  #pragma unroll
  for (int mt = 0; mt < 4; ++mt)
    #pragma unroll
    for (int nt = 0; nt < 4; ++nt){
      int col = (ntb + nt)*16 + l15;
      #pragma unroll
      for (int r = 0; r < 4; ++r)
        dst[(size_t)(rowbase + mt*16 + q*4 + r)*256 + col] = acc[mt][nt][r] * alpha;
    }
}

// ---------- reduce k-split slabs + BN3 stats + materialize h3 ----------
__global__ __launch_bounds__(256) void k_fin3f(const float* __restrict__ h3p, float* __restrict__ h3,
                                               float* __restrict__ s3, float* __restrict__ q3){
  int jb = blockIdx.x, ns = blockIdx.y, t = threadIdx.x;
  int jj = t & 31, nn = t >> 5;
  int j = jb*32 + jj;
  float s1 = 0.f, s2 = 0.f;
  for (int i = nn; i < 128; i += 8){
    int n = i*8 + ns;
    float v = 0.f;
    #pragma unroll 8
    for (int kb = 0; kb < 16; ++kb) v += h3p[(size_t)kb*262144 + n*256 + j];
    h3[n*256 + j] = v;
    s1 += v; s2 += v*v;
  }
  __shared__ float l1[256], l2[256];
  l1[t] = s1; l2[t] = s2;
  __syncthreads();
  if (t < 32){
    float a = 0.f, b = 0.f;
    #pragma unroll
    for (int k = 0; k < 8; ++k){ a += l1[t+32*k]; b += l2[t+32*k]; }
    atomicAdd(s3 + jb*32 + t, a); atomicAdd(q3 + jb*32 + t, b);
  }
}

// ---------- fc2: relu(bn3(h3)) @ sign(wfc2)^T -> out[1024,10] fp32 (BN3 params inline) ----------
__global__ __launch_bounds__(64) void k_fc2(const float* __restrict__ h3, const float* __restrict__ qwfc2,
                                            const float* __restrict__ absum,
                                            const float* __restrict__ s3, const float* __restrict__ q3,
                                            const float* __restrict__ g3, const float* __restrict__ b3,
                                            float* __restrict__ out){
  int n = blockIdx.x, lane = threadIdx.x;
  float a[4];
  #pragma unroll
  for (int i = 0; i < 4; ++i){
    int j = lane + 64*i;
    float m = s3[j] * (1.f/1024.f);
    float var = q3[j] * (1.f/1024.f) - m*m;
    float sc = g3[j] * rsqrtf(var + 1e-5f);
    float v = h3[(size_t)n*256 + j] * sc + (b3[j] - m*sc);
    a[i] = fmaxf(v, 0.f);
  }
  float alpha = absum[3] * (1.f/2560.f);
  #pragma unroll
  for (int k = 0; k < 10; ++k){
    float p = 0.f;
    #pragma unroll
    for (int i = 0; i < 4; ++i) p += a[i] * qwfc2[k*256 + lane + 64*i];
    #pragma unroll
    for (int off = 32; off > 0; off >>= 1) p += __shfl_down(p, off);
    if (lane == 0) out[n*10 + k] = p * alpha;
  }
}

extern "C" void kernel_launch(void* const* d_in, const int* in_sizes, int n_in,
                              void* d_out, int out_size, void* d_ws, size_t ws_size,
                              hipStream_t stream){
  (void)in_sizes; (void)n_in; (void)out_size; (void)ws_size;
  const float* x    = (const float*)d_in[0];
  const float* w1   = (const float*)d_in[1];
  const float* g1   = (const float*)d_in[2];
  const float* b1   = (const float*)d_in[3];
  const float* w2   = (const float*)d_in[4];
  const float* g2   = (const float*)d_in[5];
  const float* b2   = (const float*)d_in[6];
  const float* wfc1 = (const float*)d_in[7];
  const float* g3   = (const float*)d_in[8];
  const float* b3   = (const float*)d_in[9];
  const float* wfc2 = (const float*)d_in[10];
  float* out = (float*)d_out;

  float* wsf = (float*)d_ws;
  char*  wsb = (char*)d_ws;
  float* absum = wsf;
  float* s1 = wsf + 16;   float* q1 = wsf + 80;
  float* s2 = wsf + 144;  float* q2 = wsf + 272;
  float* s3 = wsf + 1024; float* q3 = wsf + 1280;
  u16*   qw1b  = (u16*)(wsf + 4096);                 // 2048 u16 conv1 B-frags
  u16*   qw2b  = (u16*)(wsb + (64u << 10));          // 144 KB bf16 B-frags
  float* qwfc2 = (float*)(wsb + (256u << 10));       // 10 KB fp32
  float* h3    = (float*)(wsb + (1ull << 20));       // 1 MB fp32 [1024][256]
  u16*   qfc1b = (u16*)(wsb + (2ull << 20));         // 4 MB bf16 B-frags
  u16*   p1t   = (u16*)(wsb + (8ull << 20) + 4096);  // 32 MB bf16 [1024][256][64]
  u16*   p2    = (u16*)(wsb + (112ull << 20));       // 16 MB bf16 [1024][64][128] pooled raw -> bn2 in place
  float* h3p   = (float*)(wsb + (128ull << 20));     // 16 MB fp32 [16][1024][256]

  hipMemsetAsync(wsf, 0, 2560 * sizeof(float), stream);
  k_absum<<<98, 256, 0, stream>>>(w1, w2, wfc1, wfc2, absum);
  k_signgen<<<8498, 256, 0, stream>>>(w1, w2, wfc1, wfc2, qw1b, qw2b, qfc1b, qwfc2);
  k_conv1m<<<1024, 256, 0, stream>>>(x, qw1b, absum, p1t, s1, q1);
  k_conv2m<<<1024, 256, 0, stream>>>(p1t, qw2b, absum, s1, q1, g1, b1, p2, s2, q2);
  k_bn2<<<4096, 256, 0, stream>>>(p2, s2, q2, g2, b2);
  k_fc1m<<<dim3(8, 2, 16), 256, 0, stream>>>(p2, qfc1b, absum, h3p);
  k_fin3f<<<dim3(8, 8), 256, 0, stream>>>(h3p, h3, s3, q3);
  k_fc2<<<1024, 64, 0, stream>>>(h3, qwfc2, absum, s3, q3, g3, b3, out);
}